// Round 3
// baseline (6719.907 us; speedup 1.0000x reference)
//
#include <hip/hip_runtime.h>
#include <math.h>

// Problem constants
#define B_   8
#define L_   512
#define LP_  514                 // padded rows per batch (halo row each side)
#define D_   1024
#define H_   16
#define DKH_ 64
#define FILT_ 4096
#define NLAYERS_ 6
#define ROWS_ (B_*L_)            // 4096
#define NE_   ((size_t)ROWS_*D_) // 4194304 elems per (B,L,D) tensor

typedef unsigned short ushort_t;
typedef unsigned int uint_t;
using short8 = __attribute__((ext_vector_type(8))) short;
using f32x4  = __attribute__((ext_vector_type(4))) float;

typedef const __attribute__((address_space(1))) void* gas_ptr;
typedef __attribute__((address_space(3))) void* las_ptr;
#define GLOAD_LDS16(g, s) __builtin_amdgcn_global_load_lds((gas_ptr)(g), (las_ptr)(s), 16, 0, 0)

__device__ __forceinline__ float bf2f(ushort_t h) { return __uint_as_float((uint_t)h << 16); }
__device__ __forceinline__ ushort_t f2bf(float f) {
    uint_t u = __float_as_uint(f);
    u = (u + 0x7FFFu + ((u >> 16) & 1u)) >> 16;   // RNE
    return (ushort_t)u;
}

// ---------------------------------------------------------------------------
__global__ __launch_bounds__(256) void embed_kernel(const int* __restrict__ X,
                                                    const float* __restrict__ emb,
                                                    float* __restrict__ state) {
    int row = blockIdx.x;
    int tok = X[row];
    const float4* src = (const float4*)(emb + (size_t)tok * D_);
    float4* dst = (float4*)(state + (size_t)row * D_);
    dst[threadIdx.x] = src[threadIdx.x];
}

// ---------------------------------------------------------------------------
// Precompute TIME_SIG (L x D) and POS_SIG (NLAYERS x D) once per launch.
__global__ __launch_bounds__(256) void sig_kernel(float* __restrict__ timesig,
                                                  float* __restrict__ possig) {
    int idx = blockIdx.x * 256 + threadIdx.x;      // L_*D_ = 524288
    int c = idx & (D_ - 1);
    int l = idx >> 10;
    const float log_inc = 0.0180241494559220821f;  // log(10000)/511
    int j = c & 511;
    float inv = expf(-log_inc * (float)j);
    timesig[idx] = (c < 512) ? sinf((float)l * inv) : cosf((float)l * inv);
    if (l < NLAYERS_)
        possig[idx] = (c < 512) ? sinf((float)l * inv) : cosf((float)l * inv);
}

// state += TIME_SIG[l,c] + POS_SIG[t,c]
__global__ __launch_bounds__(256) void add_sig_kernel(float* __restrict__ state,
                                                      const float* __restrict__ timesig,
                                                      const float* __restrict__ possig,
                                                      int layer_t) {
    int idx = blockIdx.x * 256 + threadIdx.x;
    int c = idx & (D_ - 1);
    int tl = idx & (L_ * D_ - 1);
    state[idx] += timesig[tl] + possig[layer_t * D_ + c];
}

// ---------------------------------------------------------------------------
__global__ __launch_bounds__(256) void act_kernel(const float* __restrict__ state,
                                                  const float* __restrict__ p_w,
                                                  const float* __restrict__ p_b,
                                                  float* __restrict__ hp, float* __restrict__ rem,
                                                  float* __restrict__ nup, float* __restrict__ uw) {
    int row = blockIdx.x;
    const float* x = state + (size_t)row * D_;
    float s = 0.f;
    for (int i = threadIdx.x; i < D_; i += 256) s += x[i] * p_w[i];
    __shared__ float red[256];
    red[threadIdx.x] = s; __syncthreads();
    for (int st = 128; st > 0; st >>= 1) {
        if (threadIdx.x < st) red[threadIdx.x] += red[threadIdx.x + st];
        __syncthreads();
    }
    if (threadIdx.x == 0) {
        float p = 1.f / (1.f + expf(-(red[0] + p_b[0])));
        float h = hp[row], r = rem[row], n = nup[row];
        float still = (h < 1.0f) ? 1.f : 0.f;
        float add = h + p * still;
        float nh     = (add > 0.9f) ? still : 0.f;
        float still2 = (add <= 0.9f) ? still : 0.f;
        h += p * still2;
        r += nh * (1.f - h);
        h += nh * r;
        n += still2 + nh;
        hp[row] = h; rem[row] = r; nup[row] = n;
        uw[row] = p * still2 + nh * r;
    }
}

// ---------------------------------------------------------------------------
// LayerNorm (ddof=1), fp32 in, split bf16 hi/lo out.  OUT_PAD: padded layout.
template<int OUT_PAD>
__global__ __launch_bounds__(256) void ln_kernel(const float* __restrict__ x,
                                                 const float* __restrict__ g,
                                                 const float* __restrict__ b,
                                                 ushort_t* __restrict__ yh,
                                                 ushort_t* __restrict__ yl) {
    int row = blockIdx.x;
    const float4* xr = (const float4*)(x + (size_t)row * D_);
    float4 v = xr[threadIdx.x];
    __shared__ float red[256];
    float s = v.x + v.y + v.z + v.w;
    red[threadIdx.x] = s; __syncthreads();
    for (int st = 128; st > 0; st >>= 1) { if (threadIdx.x < st) red[threadIdx.x] += red[threadIdx.x + st]; __syncthreads(); }
    float mu = red[0] * (1.f / D_);
    __syncthreads();
    float dx0 = v.x - mu, dx1 = v.y - mu, dx2 = v.z - mu, dx3 = v.w - mu;
    red[threadIdx.x] = dx0*dx0 + dx1*dx1 + dx2*dx2 + dx3*dx3; __syncthreads();
    for (int st = 128; st > 0; st >>= 1) { if (threadIdx.x < st) red[threadIdx.x] += red[threadIdx.x + st]; __syncthreads(); }
    float sd = sqrtf(red[0] * (1.f / (D_ - 1)));
    float inv = 1.f / (sd + 1e-6f);
    const float4* g4 = (const float4*)g;
    const float4* b4 = (const float4*)b;
    float4 gv = g4[threadIdx.x], bv = b4[threadIdx.x];
    float o0 = gv.x * dx0 * inv + bv.x;
    float o1 = gv.y * dx1 * inv + bv.y;
    float o2 = gv.z * dx2 * inv + bv.z;
    float o3 = gv.w * dx3 * inv + bv.w;
    int orow = OUT_PAD ? ((row >> 9) * LP_ + (row & (L_ - 1)) + 1) : row;
    ushort4 oh, ol;
    oh.x = f2bf(o0); ol.x = f2bf(o0 - bf2f(oh.x));
    oh.y = f2bf(o1); ol.y = f2bf(o1 - bf2f(oh.y));
    oh.z = f2bf(o2); ol.z = f2bf(o2 - bf2f(oh.z));
    oh.w = f2bf(o3); ol.w = f2bf(o3 - bf2f(oh.w));
    ((ushort4*)(yh + (size_t)orow * D_))[threadIdx.x] = oh;
    ((ushort4*)(yl + (size_t)orow * D_))[threadIdx.x] = ol;
}

// ---------------------------------------------------------------------------
// Transpose + split: dst[nbase+c][kbase+r] = split(scale * src[r][c])
__global__ __launch_bounds__(256) void transpose_split_kernel(const float* __restrict__ src,
                                                              ushort_t* __restrict__ dhi,
                                                              ushort_t* __restrict__ dlo,
                                                              int R, int C, int dstride,
                                                              int kbase, int nbase, float scale) {
    __shared__ float tile[32][33];
    int tx = threadIdx.x & 31, ty = threadIdx.x >> 5;   // 32 x 8
    int r0 = blockIdx.y * 32, c0 = blockIdx.x * 32;
#pragma unroll
    for (int i = 0; i < 4; ++i)
        tile[ty + i * 8][tx] = src[(size_t)(r0 + ty + i * 8) * C + c0 + tx] * scale;
    __syncthreads();
#pragma unroll
    for (int i = 0; i < 4; ++i) {
        int c = c0 + ty + i * 8;
        float val = tile[tx][ty + i * 8];
        ushort_t hi = f2bf(val);
        ushort_t lo = f2bf(val - bf2f(hi));
        size_t idx = (size_t)(nbase + c) * dstride + kbase + r0 + tx;
        dhi[idx] = hi; dlo[idx] = lo;
    }
}

// ---------------------------------------------------------------------------
// Zero halo rows of all four padded activation buffers
__global__ __launch_bounds__(256) void zero_halo_kernel(ushort_t* __restrict__ xh,
                                                        ushort_t* __restrict__ xl,
                                                        ushort_t* __restrict__ hh,
                                                        ushort_t* __restrict__ hl) {
    int idx = blockIdx.x * 256 + threadIdx.x;          // 81920 total
    if (idx < 16384) {
        int b = idx >> 11, r = (idx >> 10) & 1, c = idx & 1023;
        size_t o = ((size_t)b * LP_ + r * (LP_ - 1)) * D_ + c;
        xh[o] = 0; xl[o] = 0;
    } else {
        int j = idx - 16384;
        int b = j >> 13, r = (j >> 12) & 1, c = j & 4095;
        size_t o = ((size_t)b * LP_ + r * (LP_ - 1)) * FILT_ + c;
        hh[o] = 0; hl[o] = 0;
    }
}

// ---------------------------------------------------------------------------
// Pipelined bf16x3 MFMA GEMM: C = epi( A @ Bt^T ), A ~ Ahi+Alo, B ~ Bhi+Blo.
// BK=32, double-buffered LDS.  T3/T4 schedule: stage(i+1) issued first, then
// COUNTED s_waitcnt vmcnt(G) (G = loads/thread/stage) -> only stage(i) must
// have landed; stage(i+1)'s loads stay in flight across both barriers (never
// drain to 0 in the main loop).  B1 barrier = all waves' stage(i) landed;
// B2 barrier after MFMA = all waves done reading buf before next overwrite.
// Wave tile 64x64 (MF=NF=4): FLOP/LDS-byte ratio WM*WN/(WM+WN)=32 -- LDS pipe
// demand ~= MFMA pipe demand (vs 21.3 for 64x32, which was LDS-BW-bound @30%).
// LDS chunk layout: 16B chunk q = p*8+s (p = row-pair) holds global
// (row = 2p + (cs>>2), kchunk = cs&3) with cs = s ^ (p&7)  ->  ds_read_b128
// conflict-free, gload_lds dest stays linear (rule #21).
// PAD: A is im2col view of padded (B, LP_, Din).  OUT_MODE: 0=f32 store,
// 1=f32 accumulate, 3=split bf16 store padded.  FUSE_PREV (OUT_MODE 1 only):
// prev = state_new*uw + prev*(1-uw) fused into the epilogue.
template<int BM, int BN, int WAVES_M, int WAVES_N, int OCC, int PAD,
         int DIN_SHIFT, int OUT_MODE, int RELU, int HAS_BIAS, int FUSE_PREV>
__global__ __launch_bounds__(WAVES_M*WAVES_N*64, OCC)
void mfma_gemm_pipe(const ushort_t* __restrict__ Ahi,
                    const ushort_t* __restrict__ Alo,
                    const ushort_t* __restrict__ Bhi,
                    const ushort_t* __restrict__ Blo,
                    void* __restrict__ C, ushort_t* __restrict__ Clo,
                    const float* __restrict__ bias,
                    float* __restrict__ prevbuf, const float* __restrict__ uwv,
                    int M, int N, int K) {
    constexpr int NW = WAVES_M * WAVES_N;
    constexpr int NT = NW * 64;
    constexpr int WM = BM / WAVES_M;
    constexpr int WN = BN / WAVES_N;
    constexpr int MF = WM / 16;
    constexpr int NF = WN / 16;
    constexpr int MH = MF / 2;
    constexpr int AITER = (BM * 4) / NT;   // A 16B-chunks per thread per tile
    constexpr int BITER = (BN * 4) / NT;
    constexpr int G = 2 * (AITER + BITER); // gload_lds per thread per stage
    static_assert(G == 6 || G == 8, "vmcnt literal table");
    __shared__ __align__(16) ushort_t AsH[2][BM * 32];
    __shared__ __align__(16) ushort_t AsL[2][BM * 32];
    __shared__ __align__(16) ushort_t BsH[2][BN * 32];
    __shared__ __align__(16) ushort_t BsL[2][BN * 32];
    const int tid = threadIdx.x;
    const int w = tid >> 6, l = tid & 63;
    const int lm = l & 15, lc = l >> 4;
    // GROUP_M=8 swizzle (gridDim.y multiple of 8)
    const int bid = blockIdx.y * gridDim.x + blockIdx.x;
    const int stripe = 8 * gridDim.x;
    const int m0 = ((bid / stripe) * 8 + (bid & 7)) * BM;
    const int n0 = ((bid % stripe) >> 3) * BN;
    const int wm = (w / WAVES_N) * WM;
    const int wn = (w % WAVES_N) * WN;

    f32x4 acc[MF][NF];
#pragma unroll
    for (int i = 0; i < MF; ++i)
#pragma unroll
        for (int j = 0; j < NF; ++j) acc[i][j] = (f32x4)0.f;

    auto stage = [&](int k0, int buf) {
        int tap = 0, c0 = k0;
        if (PAD) { tap = k0 >> DIN_SHIFT; c0 = k0 & ((1 << DIN_SHIFT) - 1); }
#pragma unroll
        for (int i = 0; i < AITER; ++i) {
            int q = i * NT + tid;
            int p = q >> 3, s = q & 7;
            int cs = s ^ (p & 7);
            int grow = p * 2 + (cs >> 2);
            int gk = (cs & 3) * 8;
            size_t goff;
            if (PAD) {
                int row = m0 + grow;
                int rg = (row >> 9) * LP_ + (row & (L_ - 1)) + tap;
                goff = ((size_t)rg << DIN_SHIFT) + c0 + gk;
            } else {
                goff = (size_t)(m0 + grow) * K + k0 + gk;
            }
            size_t lo = (size_t)q * 8;
            GLOAD_LDS16(Ahi + goff, &AsH[buf][lo]);
            GLOAD_LDS16(Alo + goff, &AsL[buf][lo]);
        }
#pragma unroll
        for (int i = 0; i < BITER; ++i) {
            int q = i * NT + tid;
            int p = q >> 3, s = q & 7;
            int cs = s ^ (p & 7);
            int grow = p * 2 + (cs >> 2);
            int gk = (cs & 3) * 8;
            size_t goff = (size_t)(n0 + grow) * K + k0 + gk;
            size_t lo = (size_t)q * 8;
            GLOAD_LDS16(Bhi + goff, &BsH[buf][lo]);
            GLOAD_LDS16(Blo + goff, &BsL[buf][lo]);
        }
    };

    // swizzled ds_read of one short8 fragment: row r, k-chunk c
    auto ldf = [&](const ushort_t* base, int r, int c) -> short8 {
        int p = r >> 1;
        int s = (((r & 1) << 2) | c) ^ (p & 7);
        return *(const short8*)(base + (size_t)((p << 3) + s) * 8);
    };

    int cur = 0;
    stage(0, 0);

    for (int k0 = 0; k0 < K; k0 += 32) {
        // issue next tile's staging first, then COUNTED wait: only the
        // previous stage (G oldest loads) must have landed.
        if (k0 + 32 < K) {
            stage(k0 + 32, cur ^ 1);
            if constexpr (G == 6) asm volatile("s_waitcnt vmcnt(6)" ::: "memory");
            else                  asm volatile("s_waitcnt vmcnt(8)" ::: "memory");
        } else {
            asm volatile("s_waitcnt vmcnt(0)" ::: "memory");
        }
        __builtin_amdgcn_s_barrier();      // B1: buf[cur] valid for all waves

        short8 bfh[NF], bfl[NF];
#pragma unroll
        for (int j = 0; j < NF; ++j) {
            int rB = wn + j * 16 + lm;
            bfh[j] = ldf(&BsH[cur][0], rB, lc);
            bfl[j] = ldf(&BsL[cur][0], rB, lc);
        }
#pragma unroll
        for (int h = 0; h < 2; ++h) {
            short8 afh[MH], afl[MH];
#pragma unroll
            for (int i = 0; i < MH; ++i) {
                int rA = wm + (h * MH + i) * 16 + lm;
                afh[i] = ldf(&AsH[cur][0], rA, lc);
                afl[i] = ldf(&AsL[cur][0], rA, lc);
            }
            __builtin_amdgcn_s_setprio(1);
#pragma unroll
            for (int i = 0; i < MH; ++i)
#pragma unroll
                for (int j = 0; j < NF; ++j) {
                    f32x4 a = acc[h * MH + i][j];
                    a = __builtin_amdgcn_mfma_f32_16x16x32_bf16(afh[i], bfh[j], a, 0, 0, 0);
                    a = __builtin_amdgcn_mfma_f32_16x16x32_bf16(afl[i], bfh[j], a, 0, 0, 0);
                    a = __builtin_amdgcn_mfma_f32_16x16x32_bf16(afh[i], bfl[j], a, 0, 0, 0);
                    acc[h * MH + i][j] = a;
                }
            __builtin_amdgcn_s_setprio(0);
        }
        __builtin_amdgcn_s_barrier();      // B2: reads of buf[cur] done block-wide
        cur ^= 1;
    }

    // epilogue.  C/D layout: col = lane&15, row = (lane>>4)*4 + reg
#pragma unroll
    for (int i = 0; i < MF; ++i) {
#pragma unroll
        for (int j = 0; j < NF; ++j) {
#pragma unroll
            for (int r = 0; r < 4; ++r) {
                int row = m0 + wm + i * 16 + lc * 4 + r;
                int col = n0 + wn + j * 16 + lm;
                float v = acc[i][j][r];
                if (HAS_BIAS) v += bias[col];
                if (RELU) v = fmaxf(v, 0.f);
                size_t off;
                if (OUT_MODE == 3) off = (size_t)((row >> 9) * LP_ + (row & (L_ - 1)) + 1) * N + col;
                else               off = (size_t)row * N + col;
                if (OUT_MODE == 0) {
                    ((float*)C)[off] = v;
                } else if (OUT_MODE == 1) {
                    float* Cf = (float*)C;
                    float s2 = Cf[off] + v;
                    Cf[off] = s2;
                    if (FUSE_PREV) {
                        float u = uwv[row];
                        prevbuf[off] = s2 * u + prevbuf[off] * (1.f - u);
                    }
                } else {
                    ushort_t hi = f2bf(v);
                    ((ushort_t*)C)[off] = hi;
                    Clo[off] = f2bf(v - bf2f(hi));
                }
            }
        }
    }
}

// ---------------------------------------------------------------------------
// V transpose+split: Vt[b,h,d,key] (hi/lo bf16) from qkv fp32 V-section.
__global__ __launch_bounds__(256) void vt_kernel(const float* __restrict__ qkv,
                                                 ushort_t* __restrict__ Vth,
                                                 ushort_t* __restrict__ Vtl) {
    __shared__ float t[64][65];
    int kt = blockIdx.x, h = blockIdx.y, b = blockIdx.z;
    int tx = threadIdx.x & 63, ty = threadIdx.x >> 6;  // 64 x 4
#pragma unroll
    for (int i = 0; i < 16; ++i) {
        int r = ty + i * 4;            // key within tile
        t[r][tx] = qkv[(size_t)(b * L_ + kt * 64 + r) * (3 * D_) + 2 * D_ + h * DKH_ + tx];
    }
    __syncthreads();
#pragma unroll
    for (int i = 0; i < 16; ++i) {
        int d = ty + i * 4;
        float v = t[tx][d];            // key=tx, dim=d
        size_t o = ((size_t)((b * H_ + h) * DKH_ + d)) * L_ + kt * 64 + tx;
        ushort_t hj = f2bf(v);
        Vth[o] = hj; Vtl[o] = f2bf(v - bf2f(hj));
    }
}

// ---------------------------------------------------------------------------
// Flash MFMA attention, bf16x3 split precision (~fp32), online softmax.
__global__ __launch_bounds__(256, 2) void fattn_kernel(const float* __restrict__ qkv,
                                                       const ushort_t* __restrict__ Vth,
                                                       const ushort_t* __restrict__ Vtl,
                                                       ushort_t* __restrict__ ctxh,
                                                       ushort_t* __restrict__ ctxl) {
    __shared__ __align__(16) ushort_t Ph[4][32 * 136];
    __shared__ __align__(16) ushort_t Pl[4][32 * 136];
    int qt = blockIdx.x, h = blockIdx.y, b = blockIdx.z;
    int w = threadIdx.x >> 6, l = threadIdx.x & 63;
    int lm = l & 15, lq = l >> 4;
    int q0 = qt * 128 + w * 32;

    short8 qfh[2][2], qfl[2][2];
#pragma unroll
    for (int mt = 0; mt < 2; ++mt)
#pragma unroll
        for (int ks = 0; ks < 2; ++ks) {
            const float* qp = qkv + (size_t)(b * L_ + q0 + mt * 16 + lm) * (3 * D_)
                              + h * DKH_ + ks * 32 + lq * 8;
            short8 hi, lo;
#pragma unroll
            for (int j = 0; j < 8; ++j) {
                float x = qp[j];
                ushort_t hj = f2bf(x);
                hi[j] = (short)hj;
                lo[j] = (short)f2bf(x - bf2f(hj));
            }
            qfh[mt][ks] = hi; qfl[mt][ks] = lo;
        }

    float mrow[2][4], lrow[2][4];
    f32x4 oacc[2][4];
#pragma unroll
    for (int mt = 0; mt < 2; ++mt)
#pragma unroll
        for (int r = 0; r < 4; ++r) { mrow[mt][r] = -3.0e38f; lrow[mt][r] = 0.f; }
#pragma unroll
    for (int mt = 0; mt < 2; ++mt)
#pragma unroll
        for (int nt = 0; nt < 4; ++nt) oacc[mt][nt] = (f32x4)0.f;

    for (int c = 0; c < 4; ++c) {           // key chunks of 128
        f32x4 s[2][8];
#pragma unroll
        for (int mt = 0; mt < 2; ++mt)
#pragma unroll
            for (int nt = 0; nt < 8; ++nt) s[mt][nt] = (f32x4)0.f;

#pragma unroll
        for (int nt = 0; nt < 8; ++nt) {
#pragma unroll
            for (int ks = 0; ks < 2; ++ks) {
                const float* kp = qkv + (size_t)(b * L_ + c * 128 + nt * 16 + lm) * (3 * D_)
                                  + D_ + h * DKH_ + ks * 32 + lq * 8;
                short8 kh, kl;
#pragma unroll
                for (int j = 0; j < 8; ++j) {
                    float x = kp[j];
                    ushort_t hj = f2bf(x);
                    kh[j] = (short)hj;
                    kl[j] = (short)f2bf(x - bf2f(hj));
                }
#pragma unroll
                for (int mt = 0; mt < 2; ++mt) {
                    s[mt][nt] = __builtin_amdgcn_mfma_f32_16x16x32_bf16(qfh[mt][ks], kh, s[mt][nt], 0, 0, 0);
                    s[mt][nt] = __builtin_amdgcn_mfma_f32_16x16x32_bf16(qfl[mt][ks], kh, s[mt][nt], 0, 0, 0);
                    s[mt][nt] = __builtin_amdgcn_mfma_f32_16x16x32_bf16(qfh[mt][ks], kl, s[mt][nt], 0, 0, 0);
                }
            }
        }

#pragma unroll
        for (int mt = 0; mt < 2; ++mt) {
#pragma unroll
            for (int r = 0; r < 4; ++r) {
                float cm = s[mt][0][r];
#pragma unroll
                for (int nt = 1; nt < 8; ++nt) cm = fmaxf(cm, s[mt][nt][r]);
                cm = fmaxf(cm, __shfl_xor(cm, 1));
                cm = fmaxf(cm, __shfl_xor(cm, 2));
                cm = fmaxf(cm, __shfl_xor(cm, 4));
                cm = fmaxf(cm, __shfl_xor(cm, 8));
                float mnew = fmaxf(mrow[mt][r], cm);
                float alpha = expf(mrow[mt][r] - mnew);
                mrow[mt][r] = mnew;
                float ps = 0.f;
                int rw = mt * 16 + lq * 4 + r;
#pragma unroll
                for (int nt = 0; nt < 8; ++nt) {
                    float p = expf(s[mt][nt][r] - mnew);
                    ps += p;
                    ushort_t hj = f2bf(p);
                    int cl = nt * 16 + lm;
                    Ph[w][rw * 136 + cl] = hj;
                    Pl[w][rw * 136 + cl] = f2bf(p - bf2f(hj));
                }
                ps += __shfl_xor(ps, 1);
                ps += __shfl_xor(ps, 2);
                ps += __shfl_xor(ps, 4);
                ps += __shfl_xor(ps, 8);
                lrow[mt][r] = lrow[mt][r] * alpha + ps;
#pragma unroll
                for (int nt = 0; nt < 4; ++nt) oacc[mt][nt][r] *= alpha;
            }
        }
        asm volatile("s_waitcnt lgkmcnt(0)" ::: "memory");

#pragma unroll
        for (int ks = 0; ks < 4; ++ks) {
            short8 pah[2], pal[2];
#pragma unroll
            for (int mt = 0; mt < 2; ++mt) {
                pah[mt] = *(const short8*)&Ph[w][(mt * 16 + lm) * 136 + ks * 32 + lq * 8];
                pal[mt] = *(const short8*)&Pl[w][(mt * 16 + lm) * 136 + ks * 32 + lq * 8];
            }
#pragma unroll
            for (int nt = 0; nt < 4; ++nt) {
                size_t vo = ((size_t)((b * H_ + h) * DKH_ + nt * 16 + lm)) * L_ + c * 128 + ks * 32 + lq * 8;
                short8 vh = *(const short8*)(Vth + vo);
                short8 vl = *(const short8*)(Vtl + vo);
#pragma unroll
                for (int mt = 0; mt < 2; ++mt) {
                    oacc[mt][nt] = __builtin_amdgcn_mfma_f32_16x16x32_bf16(pah[mt], vh, oacc[mt][nt], 0, 0, 0);
                    oacc[mt][nt] = __builtin_amdgcn_mfma_f32_16x16x32_bf16(pal[mt], vh, oacc[mt][nt], 0, 0, 0);
                    oacc[mt][nt] = __builtin_amdgcn_mfma_f32_16x16x32_bf16(pah[mt], vl, oacc[mt][nt], 0, 0, 0);
                }
            }
        }
        asm volatile("s_waitcnt lgkmcnt(0)" ::: "memory");
    }

#pragma unroll
    for (int mt = 0; mt < 2; ++mt) {
#pragma unroll
        for (int nt = 0; nt < 4; ++nt) {
#pragma unroll
            for (int r = 0; r < 4; ++r) {
                float v = oacc[mt][nt][r] / lrow[mt][r];
                int rowg = b * L_ + qt * 128 + w * 32 + mt * 16 + lq * 4 + r;
                int colg = h * DKH_ + nt * 16 + lm;
                size_t o = (size_t)rowg * D_ + colg;
                ushort_t hj = f2bf(v);
                ctxh[o] = hj;
                ctxl[o] = f2bf(v - bf2f(hj));
            }
        }
    }
}

// ---------------------------------------------------------------------------
__global__ __launch_bounds__(256) void prev_kernel(const float* __restrict__ state,
                                                   float* __restrict__ prev,
                                                   const float* __restrict__ uw) {
    int idx = blockIdx.x * 256 + threadIdx.x;
    int row = idx >> 10;
    float u = uw[row];
    prev[idx] = state[idx] * u + prev[idx] * (1.f - u);
}

// ---------------------------------------------------------------------------
__global__ __launch_bounds__(256) void mean_kernel(const float* __restrict__ prev,
                                                   float* __restrict__ meanbuf) {
    int idx = blockIdx.x * 256 + threadIdx.x;  // 8192
    int b = idx >> 10, d = idx & (D_ - 1);
    float s = 0.f;
    for (int l = 0; l < L_; ++l) s += prev[((size_t)(b * L_ + l) << 10) + d];
    meanbuf[idx] = s * (1.f / L_);
}

// ---------------------------------------------------------------------------
__global__ __launch_bounds__(256) void final_kernel(const float* __restrict__ meanbuf,
                                                    const float* __restrict__ W_out,
                                                    const float* __restrict__ b_out,
                                                    const float* __restrict__ rem,
                                                    const float* __restrict__ nup,
                                                    float* __restrict__ out) {
    int tid = threadIdx.x;
    int grp = tid >> 3;
    int lane = tid & 7;
    int b = grp >> 2, j = grp & 3;
    float s = 0.f;
    for (int d2 = lane; d2 < D_; d2 += 8) s += meanbuf[b * D_ + d2] * W_out[d2 * 4 + j];
    for (int st = 4; st >= 1; st >>= 1) s += __shfl_down(s, st, 8);
    __shared__ float ah[32];
    if (lane == 0) ah[grp] = s + b_out[j];
    __syncthreads();
    if (tid < 8) {
        float a0 = ah[tid * 4 + 0], a1 = ah[tid * 4 + 1], a2 = ah[tid * 4 + 2], a3 = ah[tid * 4 + 3];
        out[tid * 4 + 0] = a0; out[tid * 4 + 1] = a1; out[tid * 4 + 2] = a2; out[tid * 4 + 3] = a3;
        float mx = fmaxf(fmaxf(a0, a1), fmaxf(a2, a3));
        float e0 = expf(a0 - mx), e1 = expf(a1 - mx), e2 = expf(a2 - mx), e3 = expf(a3 - mx);
        float sm = e0 + e1 + e2 + e3;
        out[32 + tid * 4 + 0] = e0 / sm; out[32 + tid * 4 + 1] = e1 / sm;
        out[32 + tid * 4 + 2] = e2 / sm; out[32 + tid * 4 + 3] = e3 / sm;
    }
    for (int i = tid; i < ROWS_; i += 256) {
        out[64 + i] = rem[i];
        out[64 + ROWS_ + i] = nup[i];
    }
}

// ---------------------------------------------------------------------------
extern "C" void kernel_launch(void* const* d_in, const int* in_sizes, int n_in,
                              void* d_out, int out_size, void* d_ws, size_t ws_size,
                              hipStream_t stream) {
    const int*   X     = (const int*)  d_in[0];
    const float* emb   = (const float*)d_in[1];
    const float* p_w   = (const float*)d_in[2];
    const float* p_b   = (const float*)d_in[3];
    const float* Wq    = (const float*)d_in[4];
    const float* Wk    = (const float*)d_in[5];
    const float* Wv    = (const float*)d_in[6];
    const float* Wo    = (const float*)d_in[7];
    const float* ln1_g = (const float*)d_in[8];
    const float* ln1_b = (const float*)d_in[9];
    const float* ln2_g = (const float*)d_in[10];
    const float* ln2_b = (const float*)d_in[11];
    const float* K1    = (const float*)d_in[12];
    const float* c1_b  = (const float*)d_in[13];
    const float* K2    = (const float*)d_in[14];
    const float* c2_b  = (const float*)d_in[15];
    const float* W_out = (const float*)d_in[16];
    const float* b_out = (const float*)d_in[17];

    char* ws = (char*)d_ws;
    size_t off = 0;
    auto alloc = [&](size_t bytes) { char* p = ws + off; off += (bytes + 255) & ~(size_t)255; return p; };

    float*    state  = (float*)alloc(NE_ * 4);
    float*    prev   = (float*)alloc(NE_ * 4);
    ushort_t* xn1h   = (ushort_t*)alloc(NE_ * 2);
    ushort_t* xn1l   = (ushort_t*)alloc(NE_ * 2);
    ushort_t* ctxh   = (ushort_t*)alloc(NE_ * 2);
    ushort_t* ctxl   = (ushort_t*)alloc(NE_ * 2);
    ushort_t* xn2ph  = (ushort_t*)alloc((size_t)B_ * LP_ * D_ * 2);
    ushort_t* xn2pl  = (ushort_t*)alloc((size_t)B_ * LP_ * D_ * 2);
    // union region (67.37 MB): [ qkv fp32 50.33 MB | Vth 8.39 | Vtl 8.39 ]
    // later aliased by h_hi|h_lo padded conv buffers
    char*     uni    = alloc((size_t)B_ * LP_ * FILT_ * 2 * 2);
    float*    qkv    = (float*)uni;
    ushort_t* Vth    = (ushort_t*)(uni + (size_t)ROWS_ * 3 * D_ * 4);
    ushort_t* Vtl    = Vth + (size_t)B_ * H_ * DKH_ * L_;
    ushort_t* hbh    = (ushort_t*)uni;
    ushort_t* hbl    = (ushort_t*)(uni + (size_t)B_ * LP_ * FILT_ * 2);
    ushort_t* WqkvTh = (ushort_t*)alloc((size_t)(3 * D_) * D_ * 2);
    ushort_t* WqkvTl = (ushort_t*)alloc((size_t)(3 * D_) * D_ * 2);
    ushort_t* WoTh   = (ushort_t*)alloc((size_t)D_ * D_ * 2);
    ushort_t* WoTl   = (ushort_t*)alloc((size_t)D_ * D_ * 2);
    ushort_t* K1Th   = (ushort_t*)alloc((size_t)FILT_ * (3 * D_) * 2);
    ushort_t* K1Tl   = (ushort_t*)alloc((size_t)FILT_ * (3 * D_) * 2);
    ushort_t* K2Th   = (ushort_t*)alloc((size_t)D_ * (3 * FILT_) * 2);
    ushort_t* K2Tl   = (ushort_t*)alloc((size_t)D_ * (3 * FILT_) * 2);
    float* timesig = (float*)alloc((size_t)L_ * D_ * 4);
    float* possig  = (float*)alloc((size_t)NLAYERS_ * D_ * 4);
    float* hp      = (float*)alloc(ROWS_ * 4);
    float* rem     = (float*)alloc(ROWS_ * 4);
    float* nup     = (float*)alloc(ROWS_ * 4);
    float* uw      = (float*)alloc(ROWS_ * 4);
    float* meanbuf = (float*)alloc(B_ * D_ * 4);

    hipMemsetAsync(prev, 0, NE_ * 4, stream);
    hipMemsetAsync(hp, 0, ROWS_ * 4, stream);
    hipMemsetAsync(rem, 0, ROWS_ * 4, stream);
    hipMemsetAsync(nup, 0, ROWS_ * 4, stream);

    // weight prep: transpose + split; fold q-scale 0.125 (exact pow2) into Wq
    transpose_split_kernel<<<dim3(32, 32), 256, 0, stream>>>(Wq, WqkvTh, WqkvTl, D_, D_, D_, 0, 0,       0.125f);
    transpose_split_kernel<<<dim3(32, 32), 256, 0, stream>>>(Wk, WqkvTh, WqkvTl, D_, D_, D_, 0, D_,      1.f);
    transpose_split_kernel<<<dim3(32, 32), 256, 0, stream>>>(Wv, WqkvTh, WqkvTl, D_, D_, D_, 0, 2 * D_,  1.f);
    transpose_split_kernel<<<dim3(32, 32), 256, 0, stream>>>(Wo, WoTh, WoTl, D_, D_, D_, 0, 0, 1.f);
    for (int t = 0; t < 3; ++t) {
        transpose_split_kernel<<<dim3(128, 32), 256, 0, stream>>>(
            K1 + (size_t)t * D_ * FILT_, K1Th, K1Tl, D_, FILT_, 3 * D_, t * D_, 0, 1.f);
        transpose_split_kernel<<<dim3(32, 128), 256, 0, stream>>>(
            K2 + (size_t)t * FILT_ * D_, K2Th, K2Tl, FILT_, D_, 3 * FILT_, t * FILT_, 0, 1.f);
    }
    sig_kernel<<<(L_ * D_) / 256, 256, 0, stream>>>(timesig, possig);

    embed_kernel<<<ROWS_, 256, 0, stream>>>(X, emb, state);

    dim3 gQKV(3 * D_ / 128, ROWS_ / 128);   // (24, 32)  128x128, 2 blk/CU
    dim3 gWo(D_ / 128, ROWS_ / 128);        // (8, 32)   128x128, 2 blk/CU
    dim3 gC1(FILT_ / 256, ROWS_ / 256);     // (16, 16)  256x256, 1 blk/CU
    dim3 gC2(D_ / 128, ROWS_ / 128);        // (8, 32)   128x128, 2 blk/CU

    for (int t = 0; t < NLAYERS_; ++t) {
        add_sig_kernel<<<NE_ / 256, 256, 0, stream>>>(state, timesig, possig, t);
        act_kernel<<<ROWS_, 256, 0, stream>>>(state, p_w, p_b, hp, rem, nup, uw);
        ln_kernel<0><<<ROWS_, 256, 0, stream>>>(state, ln1_g, ln1_b, xn1h, xn1l);

        // qkv = xn @ [0.125*Wq | Wk | Wv]  (fp32 out)
        mfma_gemm_pipe<128,128,2,2, 2, 0,0,0,0,0,0><<<gQKV, 256, 0, stream>>>(
            xn1h, xn1l, WqkvTh, WqkvTl, qkv, nullptr, nullptr, nullptr, nullptr,
            ROWS_, 3 * D_, D_);
        vt_kernel<<<dim3(L_ / 64, H_, B_), 256, 0, stream>>>(qkv, Vth, Vtl);
        fattn_kernel<<<dim3(L_ / 128, H_, B_), 256, 0, stream>>>(qkv, Vth, Vtl, ctxh, ctxl);

        // state += ctx @ Wo
        mfma_gemm_pipe<128,128,2,2, 2, 0,0,1,0,0,0><<<gWo, 256, 0, stream>>>(
            ctxh, ctxl, WoTh, WoTl, state, nullptr, nullptr, nullptr, nullptr,
            ROWS_, D_, D_);

        // re-zero conv halos (h region aliases qkv/Vt — now dead)
        zero_halo_kernel<<<81920 / 256, 256, 0, stream>>>(xn2ph, xn2pl, hbh, hbl);

        ln_kernel<1><<<ROWS_, 256, 0, stream>>>(state, ln2_g, ln2_b, xn2ph, xn2pl);

        // h = relu(conv1(xn2) + c1_b)  -> padded split bf16
        mfma_gemm_pipe<256,256,2,4, 2, 1,10,3,1,1,0><<<gC1, 512, 0, stream>>>(
            xn2ph, xn2pl, K1Th, K1Tl, hbh, hbl, c1_b, nullptr, nullptr,
            ROWS_, FILT_, 3 * D_);
        // state += conv2(h) + c2_b ; fused: prev = state*uw + prev*(1-uw)
        mfma_gemm_pipe<128,128,2,2, 2, 1,12,1,0,1,1><<<gC2, 256, 0, stream>>>(
            hbh, hbl, K2Th, K2Tl, state, nullptr, c2_b, prev, uw,
            ROWS_, D_, 3 * FILT_);
    }

    mean_kernel<<<(B_ * D_) / 256, 256, 0, stream>>>(prev, meanbuf);
    final_kernel<<<1, 256, 0, stream>>>(meanbuf, W_out, b_out, rem, nup, (float*)d_out);
}

// Round 4
// 5466.776 us; speedup vs baseline: 1.2292x; 1.2292x over previous
//
#include <hip/hip_runtime.h>
#include <math.h>

// Problem constants
#define B_   8
#define L_   512
#define LP_  514                 // padded rows per batch (halo row each side)
#define D_   1024
#define H_   16
#define DKH_ 64
#define FILT_ 4096
#define NLAYERS_ 6
#define ROWS_ (B_*L_)            // 4096
#define NE_   ((size_t)ROWS_*D_) // 4194304 elems per (B,L,D) tensor

typedef unsigned short ushort_t;
typedef unsigned int uint_t;
using short8 = __attribute__((ext_vector_type(8))) short;
using f32x4  = __attribute__((ext_vector_type(4))) float;

typedef const __attribute__((address_space(1))) void* gas_ptr;
typedef __attribute__((address_space(3))) void* las_ptr;
#define GLOAD_LDS16(g, s) __builtin_amdgcn_global_load_lds((gas_ptr)(g), (las_ptr)(s), 16, 0, 0)

__device__ __forceinline__ float bf2f(ushort_t h) { return __uint_as_float((uint_t)h << 16); }
__device__ __forceinline__ ushort_t f2bf(float f) {
    uint_t u = __float_as_uint(f);
    u = (u + 0x7FFFu + ((u >> 16) & 1u)) >> 16;   // RNE
    return (ushort_t)u;
}

// ---------------------------------------------------------------------------
__global__ __launch_bounds__(256) void embed_kernel(const int* __restrict__ X,
                                                    const float* __restrict__ emb,
                                                    float* __restrict__ state) {
    int row = blockIdx.x;
    int tok = X[row];
    const float4* src = (const float4*)(emb + (size_t)tok * D_);
    float4* dst = (float4*)(state + (size_t)row * D_);
    dst[threadIdx.x] = src[threadIdx.x];
}

// ---------------------------------------------------------------------------
// Precompute TIME_SIG (L x D) and POS_SIG (NLAYERS x D) once per launch.
__global__ __launch_bounds__(256) void sig_kernel(float* __restrict__ timesig,
                                                  float* __restrict__ possig) {
    int idx = blockIdx.x * 256 + threadIdx.x;      // L_*D_ = 524288
    int c = idx & (D_ - 1);
    int l = idx >> 10;
    const float log_inc = 0.0180241494559220821f;  // log(10000)/511
    int j = c & 511;
    float inv = expf(-log_inc * (float)j);
    timesig[idx] = (c < 512) ? sinf((float)l * inv) : cosf((float)l * inv);
    if (l < NLAYERS_)
        possig[idx] = (c < 512) ? sinf((float)l * inv) : cosf((float)l * inv);
}

// state += TIME_SIG[l,c] + POS_SIG[t,c]
__global__ __launch_bounds__(256) void add_sig_kernel(float* __restrict__ state,
                                                      const float* __restrict__ timesig,
                                                      const float* __restrict__ possig,
                                                      int layer_t) {
    int idx = blockIdx.x * 256 + threadIdx.x;
    int c = idx & (D_ - 1);
    int tl = idx & (L_ * D_ - 1);
    state[idx] += timesig[tl] + possig[layer_t * D_ + c];
}

// ---------------------------------------------------------------------------
__global__ __launch_bounds__(256) void act_kernel(const float* __restrict__ state,
                                                  const float* __restrict__ p_w,
                                                  const float* __restrict__ p_b,
                                                  float* __restrict__ hp, float* __restrict__ rem,
                                                  float* __restrict__ nup, float* __restrict__ uw) {
    int row = blockIdx.x;
    const float* x = state + (size_t)row * D_;
    float s = 0.f;
    for (int i = threadIdx.x; i < D_; i += 256) s += x[i] * p_w[i];
    __shared__ float red[256];
    red[threadIdx.x] = s; __syncthreads();
    for (int st = 128; st > 0; st >>= 1) {
        if (threadIdx.x < st) red[threadIdx.x] += red[threadIdx.x + st];
        __syncthreads();
    }
    if (threadIdx.x == 0) {
        float p = 1.f / (1.f + expf(-(red[0] + p_b[0])));
        float h = hp[row], r = rem[row], n = nup[row];
        float still = (h < 1.0f) ? 1.f : 0.f;
        float add = h + p * still;
        float nh     = (add > 0.9f) ? still : 0.f;
        float still2 = (add <= 0.9f) ? still : 0.f;
        h += p * still2;
        r += nh * (1.f - h);
        h += nh * r;
        n += still2 + nh;
        hp[row] = h; rem[row] = r; nup[row] = n;
        uw[row] = p * still2 + nh * r;
    }
}

// ---------------------------------------------------------------------------
// LayerNorm (ddof=1), fp32 in, split bf16 hi/lo out.  OUT_PAD: padded layout.
template<int OUT_PAD>
__global__ __launch_bounds__(256) void ln_kernel(const float* __restrict__ x,
                                                 const float* __restrict__ g,
                                                 const float* __restrict__ b,
                                                 ushort_t* __restrict__ yh,
                                                 ushort_t* __restrict__ yl) {
    int row = blockIdx.x;
    const float4* xr = (const float4*)(x + (size_t)row * D_);
    float4 v = xr[threadIdx.x];
    __shared__ float red[256];
    float s = v.x + v.y + v.z + v.w;
    red[threadIdx.x] = s; __syncthreads();
    for (int st = 128; st > 0; st >>= 1) { if (threadIdx.x < st) red[threadIdx.x] += red[threadIdx.x + st]; __syncthreads(); }
    float mu = red[0] * (1.f / D_);
    __syncthreads();
    float dx0 = v.x - mu, dx1 = v.y - mu, dx2 = v.z - mu, dx3 = v.w - mu;
    red[threadIdx.x] = dx0*dx0 + dx1*dx1 + dx2*dx2 + dx3*dx3; __syncthreads();
    for (int st = 128; st > 0; st >>= 1) { if (threadIdx.x < st) red[threadIdx.x] += red[threadIdx.x + st]; __syncthreads(); }
    float sd = sqrtf(red[0] * (1.f / (D_ - 1)));
    float inv = 1.f / (sd + 1e-6f);
    const float4* g4 = (const float4*)g;
    const float4* b4 = (const float4*)b;
    float4 gv = g4[threadIdx.x], bv = b4[threadIdx.x];
    float o0 = gv.x * dx0 * inv + bv.x;
    float o1 = gv.y * dx1 * inv + bv.y;
    float o2 = gv.z * dx2 * inv + bv.z;
    float o3 = gv.w * dx3 * inv + bv.w;
    int orow = OUT_PAD ? ((row >> 9) * LP_ + (row & (L_ - 1)) + 1) : row;
    ushort4 oh, ol;
    oh.x = f2bf(o0); ol.x = f2bf(o0 - bf2f(oh.x));
    oh.y = f2bf(o1); ol.y = f2bf(o1 - bf2f(oh.y));
    oh.z = f2bf(o2); ol.z = f2bf(o2 - bf2f(oh.z));
    oh.w = f2bf(o3); ol.w = f2bf(o3 - bf2f(oh.w));
    ((ushort4*)(yh + (size_t)orow * D_))[threadIdx.x] = oh;
    ((ushort4*)(yl + (size_t)orow * D_))[threadIdx.x] = ol;
}

// ---------------------------------------------------------------------------
// Transpose + split: dst[nbase+c][kbase+r] = split(scale * src[r][c])
__global__ __launch_bounds__(256) void transpose_split_kernel(const float* __restrict__ src,
                                                              ushort_t* __restrict__ dhi,
                                                              ushort_t* __restrict__ dlo,
                                                              int R, int C, int dstride,
                                                              int kbase, int nbase, float scale) {
    __shared__ float tile[32][33];
    int tx = threadIdx.x & 31, ty = threadIdx.x >> 5;   // 32 x 8
    int r0 = blockIdx.y * 32, c0 = blockIdx.x * 32;
#pragma unroll
    for (int i = 0; i < 4; ++i)
        tile[ty + i * 8][tx] = src[(size_t)(r0 + ty + i * 8) * C + c0 + tx] * scale;
    __syncthreads();
#pragma unroll
    for (int i = 0; i < 4; ++i) {
        int c = c0 + ty + i * 8;
        float val = tile[tx][ty + i * 8];
        ushort_t hi = f2bf(val);
        ushort_t lo = f2bf(val - bf2f(hi));
        size_t idx = (size_t)(nbase + c) * dstride + kbase + r0 + tx;
        dhi[idx] = hi; dlo[idx] = lo;
    }
}

// ---------------------------------------------------------------------------
// Zero halo rows of all four padded activation buffers
__global__ __launch_bounds__(256) void zero_halo_kernel(ushort_t* __restrict__ xh,
                                                        ushort_t* __restrict__ xl,
                                                        ushort_t* __restrict__ hh,
                                                        ushort_t* __restrict__ hl) {
    int idx = blockIdx.x * 256 + threadIdx.x;          // 81920 total
    if (idx < 16384) {
        int b = idx >> 11, r = (idx >> 10) & 1, c = idx & 1023;
        size_t o = ((size_t)b * LP_ + r * (LP_ - 1)) * D_ + c;
        xh[o] = 0; xl[o] = 0;
    } else {
        int j = idx - 16384;
        int b = j >> 13, r = (j >> 12) & 1, c = j & 4095;
        size_t o = ((size_t)b * LP_ + r * (LP_ - 1)) * FILT_ + c;
        hh[o] = 0; hl[o] = 0;
    }
}

// ---------------------------------------------------------------------------
// Pipelined bf16x3 MFMA GEMM: C = epi( A @ Bt^T ), A ~ Ahi+Alo, B ~ Bhi+Blo.
// BK=32, double-buffered LDS.  T3/T4 schedule: stage(i+1) issued first, then
// COUNTED s_waitcnt vmcnt(G) (G = loads/thread/stage) -> only stage(i) must
// have landed; stage(i+1)'s loads stay in flight across both barriers (never
// drain to 0 in the main loop).  B1 barrier = all waves' stage(i) landed;
// B2 barrier after MFMA = all waves done reading buf before next overwrite.
// Wave tile 64x64 (MF=NF=4): FLOP/LDS-byte ratio WM*WN/(WM+WN)=32.
// SPLITK: blockIdx.z selects a K-chunk; OUT_MODE 0 writes partial z-slice.
// Lesson (R3): resident blocks/CU is the lever -- grid must be >= 2*256.
// LDS chunk layout: 16B chunk q = p*8+s (p = row-pair) holds global
// (row = 2p + (cs>>2), kchunk = cs&3) with cs = s ^ (p&7)  ->  ds_read_b128
// conflict-free, gload_lds dest stays linear (rule #21).
// PAD: A is im2col view of padded (B, LP_, Din).  OUT_MODE: 0=f32 store
// (+z-slice), 1=f32 accumulate, 3=split bf16 store padded.
template<int BM, int BN, int WAVES_M, int WAVES_N, int OCC, int PAD,
         int DIN_SHIFT, int OUT_MODE, int RELU, int HAS_BIAS, int SPLITK>
__global__ __launch_bounds__(WAVES_M*WAVES_N*64, OCC)
void mfma_gemm_pipe(const ushort_t* __restrict__ Ahi,
                    const ushort_t* __restrict__ Alo,
                    const ushort_t* __restrict__ Bhi,
                    const ushort_t* __restrict__ Blo,
                    void* __restrict__ C, ushort_t* __restrict__ Clo,
                    const float* __restrict__ bias,
                    int M, int N, int K) {
    constexpr int NW = WAVES_M * WAVES_N;
    constexpr int NT = NW * 64;
    constexpr int WM = BM / WAVES_M;
    constexpr int WN = BN / WAVES_N;
    constexpr int MF = WM / 16;
    constexpr int NF = WN / 16;
    constexpr int MH = MF / 2;
    constexpr int AITER = (BM * 4) / NT;   // A 16B-chunks per thread per tile
    constexpr int BITER = (BN * 4) / NT;
    constexpr int G = 2 * (AITER + BITER); // gload_lds per thread per stage
    static_assert(G == 6 || G == 8, "vmcnt literal table");
    __shared__ __align__(16) ushort_t AsH[2][BM * 32];
    __shared__ __align__(16) ushort_t AsL[2][BM * 32];
    __shared__ __align__(16) ushort_t BsH[2][BN * 32];
    __shared__ __align__(16) ushort_t BsL[2][BN * 32];
    const int tid = threadIdx.x;
    const int w = tid >> 6, l = tid & 63;
    const int lm = l & 15, lc = l >> 4;
    // GROUP_M=8 swizzle (gridDim.y multiple of 8)
    const int bid = blockIdx.y * gridDim.x + blockIdx.x;
    const int stripe = 8 * gridDim.x;
    const int m0 = ((bid / stripe) * 8 + (bid & 7)) * BM;
    const int n0 = ((bid % stripe) >> 3) * BN;
    const int wm = (w / WAVES_N) * WM;
    const int wn = (w % WAVES_N) * WN;
    const int kch  = K / SPLITK;
    const int kbeg = (SPLITK > 1) ? blockIdx.z * kch : 0;
    const int kend = kbeg + kch;

    f32x4 acc[MF][NF];
#pragma unroll
    for (int i = 0; i < MF; ++i)
#pragma unroll
        for (int j = 0; j < NF; ++j) acc[i][j] = (f32x4)0.f;

    auto stage = [&](int k0, int buf) {
        int tap = 0, c0 = k0;
        if (PAD) { tap = k0 >> DIN_SHIFT; c0 = k0 & ((1 << DIN_SHIFT) - 1); }
#pragma unroll
        for (int i = 0; i < AITER; ++i) {
            int q = i * NT + tid;
            int p = q >> 3, s = q & 7;
            int cs = s ^ (p & 7);
            int grow = p * 2 + (cs >> 2);
            int gk = (cs & 3) * 8;
            size_t goff;
            if (PAD) {
                int row = m0 + grow;
                int rg = (row >> 9) * LP_ + (row & (L_ - 1)) + tap;
                goff = ((size_t)rg << DIN_SHIFT) + c0 + gk;
            } else {
                goff = (size_t)(m0 + grow) * K + k0 + gk;
            }
            size_t lo = (size_t)q * 8;
            GLOAD_LDS16(Ahi + goff, &AsH[buf][lo]);
            GLOAD_LDS16(Alo + goff, &AsL[buf][lo]);
        }
#pragma unroll
        for (int i = 0; i < BITER; ++i) {
            int q = i * NT + tid;
            int p = q >> 3, s = q & 7;
            int cs = s ^ (p & 7);
            int grow = p * 2 + (cs >> 2);
            int gk = (cs & 3) * 8;
            size_t goff = (size_t)(n0 + grow) * K + k0 + gk;
            size_t lo = (size_t)q * 8;
            GLOAD_LDS16(Bhi + goff, &BsH[buf][lo]);
            GLOAD_LDS16(Blo + goff, &BsL[buf][lo]);
        }
    };

    // swizzled ds_read of one short8 fragment: row r, k-chunk c
    auto ldf = [&](const ushort_t* base, int r, int c) -> short8 {
        int p = r >> 1;
        int s = (((r & 1) << 2) | c) ^ (p & 7);
        return *(const short8*)(base + (size_t)((p << 3) + s) * 8);
    };

    int cur = 0;
    stage(kbeg, 0);

    for (int k0 = kbeg; k0 < kend; k0 += 32) {
        // issue next tile's staging first, then COUNTED wait: only the
        // previous stage (G oldest loads) must have landed.
        if (k0 + 32 < kend) {
            stage(k0 + 32, cur ^ 1);
            if constexpr (G == 6) asm volatile("s_waitcnt vmcnt(6)" ::: "memory");
            else                  asm volatile("s_waitcnt vmcnt(8)" ::: "memory");
        } else {
            asm volatile("s_waitcnt vmcnt(0)" ::: "memory");
        }
        __builtin_amdgcn_s_barrier();      // B1: buf[cur] valid for all waves

        short8 bfh[NF], bfl[NF];
#pragma unroll
        for (int j = 0; j < NF; ++j) {
            int rB = wn + j * 16 + lm;
            bfh[j] = ldf(&BsH[cur][0], rB, lc);
            bfl[j] = ldf(&BsL[cur][0], rB, lc);
        }
#pragma unroll
        for (int h = 0; h < 2; ++h) {
            short8 afh[MH], afl[MH];
#pragma unroll
            for (int i = 0; i < MH; ++i) {
                int rA = wm + (h * MH + i) * 16 + lm;
                afh[i] = ldf(&AsH[cur][0], rA, lc);
                afl[i] = ldf(&AsL[cur][0], rA, lc);
            }
            __builtin_amdgcn_s_setprio(1);
#pragma unroll
            for (int i = 0; i < MH; ++i)
#pragma unroll
                for (int j = 0; j < NF; ++j) {
                    f32x4 a = acc[h * MH + i][j];
                    a = __builtin_amdgcn_mfma_f32_16x16x32_bf16(afh[i], bfh[j], a, 0, 0, 0);
                    a = __builtin_amdgcn_mfma_f32_16x16x32_bf16(afl[i], bfh[j], a, 0, 0, 0);
                    a = __builtin_amdgcn_mfma_f32_16x16x32_bf16(afh[i], bfl[j], a, 0, 0, 0);
                    acc[h * MH + i][j] = a;
                }
            __builtin_amdgcn_s_setprio(0);
        }
        __builtin_amdgcn_s_barrier();      // B2: reads of buf[cur] done block-wide
        cur ^= 1;
    }

    // epilogue.  C/D layout: col = lane&15, row = (lane>>4)*4 + reg
    const size_t zoff = (size_t)blockIdx.z * (size_t)M * (size_t)N;
#pragma unroll
    for (int i = 0; i < MF; ++i) {
#pragma unroll
        for (int j = 0; j < NF; ++j) {
#pragma unroll
            for (int r = 0; r < 4; ++r) {
                int row = m0 + wm + i * 16 + lc * 4 + r;
                int col = n0 + wn + j * 16 + lm;
                float v = acc[i][j][r];
                if (HAS_BIAS) v += bias[col];
                if (RELU) v = fmaxf(v, 0.f);
                size_t off;
                if (OUT_MODE == 3) off = (size_t)((row >> 9) * LP_ + (row & (L_ - 1)) + 1) * N + col;
                else               off = (size_t)row * N + col;
                if (OUT_MODE == 0) {
                    ((float*)C)[zoff + off] = v;
                } else if (OUT_MODE == 1) {
                    float* Cf = (float*)C;
                    Cf[off] += v;
                } else {
                    ushort_t hi = f2bf(v);
                    ((ushort_t*)C)[off] = hi;
                    Clo[off] = f2bf(v - bf2f(hi));
                }
            }
        }
    }
}

// ---------------------------------------------------------------------------
// Split-K reduce for conv2: state += part0 + part1 + c2_b; prev blend fused.
__global__ __launch_bounds__(256) void reduce_k_kernel(const float* __restrict__ part,
                                                       const float* __restrict__ bias,
                                                       float* __restrict__ state,
                                                       float* __restrict__ prev,
                                                       const float* __restrict__ uw) {
    int idx = blockIdx.x * 256 + threadIdx.x;      // NE_/4 float4 elems
    int row = idx >> 8;                            // 256 float4 per row (N=1024)
    int c4  = idx & 255;
    float4 p0 = ((const float4*)part)[idx];
    float4 p1 = ((const float4*)part)[(NE_ >> 2) + idx];
    float4 bv = ((const float4*)bias)[c4];
    float4 st = ((float4*)state)[idx];
    float4 pv = ((float4*)prev)[idx];
    float u = uw[row];
    float4 s;
    s.x = st.x + p0.x + p1.x + bv.x;
    s.y = st.y + p0.y + p1.y + bv.y;
    s.z = st.z + p0.z + p1.z + bv.z;
    s.w = st.w + p0.w + p1.w + bv.w;
    ((float4*)state)[idx] = s;
    pv.x = s.x * u + pv.x * (1.f - u);
    pv.y = s.y * u + pv.y * (1.f - u);
    pv.z = s.z * u + pv.z * (1.f - u);
    pv.w = s.w * u + pv.w * (1.f - u);
    ((float4*)prev)[idx] = pv;
}

// ---------------------------------------------------------------------------
// V transpose+split: Vt[b,h,d,key] (hi/lo bf16) from qkv fp32 V-section.
__global__ __launch_bounds__(256) void vt_kernel(const float* __restrict__ qkv,
                                                 ushort_t* __restrict__ Vth,
                                                 ushort_t* __restrict__ Vtl) {
    __shared__ float t[64][65];
    int kt = blockIdx.x, h = blockIdx.y, b = blockIdx.z;
    int tx = threadIdx.x & 63, ty = threadIdx.x >> 6;  // 64 x 4
#pragma unroll
    for (int i = 0; i < 16; ++i) {
        int r = ty + i * 4;            // key within tile
        t[r][tx] = qkv[(size_t)(b * L_ + kt * 64 + r) * (3 * D_) + 2 * D_ + h * DKH_ + tx];
    }
    __syncthreads();
#pragma unroll
    for (int i = 0; i < 16; ++i) {
        int d = ty + i * 4;
        float v = t[tx][d];            // key=tx, dim=d
        size_t o = ((size_t)((b * H_ + h) * DKH_ + d)) * L_ + kt * 64 + tx;
        ushort_t hj = f2bf(v);
        Vth[o] = hj; Vtl[o] = f2bf(v - bf2f(hj));
    }
}

// ---------------------------------------------------------------------------
// Flash MFMA attention, bf16x3 split precision (~fp32), online softmax.
__global__ __launch_bounds__(256, 2) void fattn_kernel(const float* __restrict__ qkv,
                                                       const ushort_t* __restrict__ Vth,
                                                       const ushort_t* __restrict__ Vtl,
                                                       ushort_t* __restrict__ ctxh,
                                                       ushort_t* __restrict__ ctxl) {
    __shared__ __align__(16) ushort_t Ph[4][32 * 136];
    __shared__ __align__(16) ushort_t Pl[4][32 * 136];
    int qt = blockIdx.x, h = blockIdx.y, b = blockIdx.z;
    int w = threadIdx.x >> 6, l = threadIdx.x & 63;
    int lm = l & 15, lq = l >> 4;
    int q0 = qt * 128 + w * 32;

    short8 qfh[2][2], qfl[2][2];
#pragma unroll
    for (int mt = 0; mt < 2; ++mt)
#pragma unroll
        for (int ks = 0; ks < 2; ++ks) {
            const float* qp = qkv + (size_t)(b * L_ + q0 + mt * 16 + lm) * (3 * D_)
                              + h * DKH_ + ks * 32 + lq * 8;
            short8 hi, lo;
#pragma unroll
            for (int j = 0; j < 8; ++j) {
                float x = qp[j];
                ushort_t hj = f2bf(x);
                hi[j] = (short)hj;
                lo[j] = (short)f2bf(x - bf2f(hj));
            }
            qfh[mt][ks] = hi; qfl[mt][ks] = lo;
        }

    float mrow[2][4], lrow[2][4];
    f32x4 oacc[2][4];
#pragma unroll
    for (int mt = 0; mt < 2; ++mt)
#pragma unroll
        for (int r = 0; r < 4; ++r) { mrow[mt][r] = -3.0e38f; lrow[mt][r] = 0.f; }
#pragma unroll
    for (int mt = 0; mt < 2; ++mt)
#pragma unroll
        for (int nt = 0; nt < 4; ++nt) oacc[mt][nt] = (f32x4)0.f;

    for (int c = 0; c < 4; ++c) {           // key chunks of 128
        f32x4 s[2][8];
#pragma unroll
        for (int mt = 0; mt < 2; ++mt)
#pragma unroll
            for (int nt = 0; nt < 8; ++nt) s[mt][nt] = (f32x4)0.f;

#pragma unroll
        for (int nt = 0; nt < 8; ++nt) {
#pragma unroll
            for (int ks = 0; ks < 2; ++ks) {
                const float* kp = qkv + (size_t)(b * L_ + c * 128 + nt * 16 + lm) * (3 * D_)
                                  + D_ + h * DKH_ + ks * 32 + lq * 8;
                short8 kh, kl;
#pragma unroll
                for (int j = 0; j < 8; ++j) {
                    float x = kp[j];
                    ushort_t hj = f2bf(x);
                    kh[j] = (short)hj;
                    kl[j] = (short)f2bf(x - bf2f(hj));
                }
#pragma unroll
                for (int mt = 0; mt < 2; ++mt) {
                    s[mt][nt] = __builtin_amdgcn_mfma_f32_16x16x32_bf16(qfh[mt][ks], kh, s[mt][nt], 0, 0, 0);
                    s[mt][nt] = __builtin_amdgcn_mfma_f32_16x16x32_bf16(qfl[mt][ks], kh, s[mt][nt], 0, 0, 0);
                    s[mt][nt] = __builtin_amdgcn_mfma_f32_16x16x32_bf16(qfh[mt][ks], kl, s[mt][nt], 0, 0, 0);
                }
            }
        }

#pragma unroll
        for (int mt = 0; mt < 2; ++mt) {
#pragma unroll
            for (int r = 0; r < 4; ++r) {
                float cm = s[mt][0][r];
#pragma unroll
                for (int nt = 1; nt < 8; ++nt) cm = fmaxf(cm, s[mt][nt][r]);
                cm = fmaxf(cm, __shfl_xor(cm, 1));
                cm = fmaxf(cm, __shfl_xor(cm, 2));
                cm = fmaxf(cm, __shfl_xor(cm, 4));
                cm = fmaxf(cm, __shfl_xor(cm, 8));
                float mnew = fmaxf(mrow[mt][r], cm);
                float alpha = expf(mrow[mt][r] - mnew);
                mrow[mt][r] = mnew;
                float ps = 0.f;
                int rw = mt * 16 + lq * 4 + r;
#pragma unroll
                for (int nt = 0; nt < 8; ++nt) {
                    float p = expf(s[mt][nt][r] - mnew);
                    ps += p;
                    ushort_t hj = f2bf(p);
                    int cl = nt * 16 + lm;
                    Ph[w][rw * 136 + cl] = hj;
                    Pl[w][rw * 136 + cl] = f2bf(p - bf2f(hj));
                }
                ps += __shfl_xor(ps, 1);
                ps += __shfl_xor(ps, 2);
                ps += __shfl_xor(ps, 4);
                ps += __shfl_xor(ps, 8);
                lrow[mt][r] = lrow[mt][r] * alpha + ps;
#pragma unroll
                for (int nt = 0; nt < 4; ++nt) oacc[mt][nt][r] *= alpha;
            }
        }
        asm volatile("s_waitcnt lgkmcnt(0)" ::: "memory");

#pragma unroll
        for (int ks = 0; ks < 4; ++ks) {
            short8 pah[2], pal[2];
#pragma unroll
            for (int mt = 0; mt < 2; ++mt) {
                pah[mt] = *(const short8*)&Ph[w][(mt * 16 + lm) * 136 + ks * 32 + lq * 8];
                pal[mt] = *(const short8*)&Pl[w][(mt * 16 + lm) * 136 + ks * 32 + lq * 8];
            }
#pragma unroll
            for (int nt = 0; nt < 4; ++nt) {
                size_t vo = ((size_t)((b * H_ + h) * DKH_ + nt * 16 + lm)) * L_ + c * 128 + ks * 32 + lq * 8;
                short8 vh = *(const short8*)(Vth + vo);
                short8 vl = *(const short8*)(Vtl + vo);
#pragma unroll
                for (int mt = 0; mt < 2; ++mt) {
                    oacc[mt][nt] = __builtin_amdgcn_mfma_f32_16x16x32_bf16(pah[mt], vh, oacc[mt][nt], 0, 0, 0);
                    oacc[mt][nt] = __builtin_amdgcn_mfma_f32_16x16x32_bf16(pal[mt], vh, oacc[mt][nt], 0, 0, 0);
                    oacc[mt][nt] = __builtin_amdgcn_mfma_f32_16x16x32_bf16(pah[mt], vl, oacc[mt][nt], 0, 0, 0);
                }
            }
        }
        asm volatile("s_waitcnt lgkmcnt(0)" ::: "memory");
    }

#pragma unroll
    for (int mt = 0; mt < 2; ++mt) {
#pragma unroll
        for (int nt = 0; nt < 4; ++nt) {
#pragma unroll
            for (int r = 0; r < 4; ++r) {
                float v = oacc[mt][nt][r] / lrow[mt][r];
                int rowg = b * L_ + qt * 128 + w * 32 + mt * 16 + lq * 4 + r;
                int colg = h * DKH_ + nt * 16 + lm;
                size_t o = (size_t)rowg * D_ + colg;
                ushort_t hj = f2bf(v);
                ctxh[o] = hj;
                ctxl[o] = f2bf(v - bf2f(hj));
            }
        }
    }
}

// ---------------------------------------------------------------------------
__global__ __launch_bounds__(256) void mean_kernel(const float* __restrict__ prev,
                                                   float* __restrict__ meanbuf) {
    int idx = blockIdx.x * 256 + threadIdx.x;  // 8192
    int b = idx >> 10, d = idx & (D_ - 1);
    float s = 0.f;
    for (int l = 0; l < L_; ++l) s += prev[((size_t)(b * L_ + l) << 10) + d];
    meanbuf[idx] = s * (1.f / L_);
}

// ---------------------------------------------------------------------------
__global__ __launch_bounds__(256) void final_kernel(const float* __restrict__ meanbuf,
                                                    const float* __restrict__ W_out,
                                                    const float* __restrict__ b_out,
                                                    const float* __restrict__ rem,
                                                    const float* __restrict__ nup,
                                                    float* __restrict__ out) {
    int tid = threadIdx.x;
    int grp = tid >> 3;
    int lane = tid & 7;
    int b = grp >> 2, j = grp & 3;
    float s = 0.f;
    for (int d2 = lane; d2 < D_; d2 += 8) s += meanbuf[b * D_ + d2] * W_out[d2 * 4 + j];
    for (int st = 4; st >= 1; st >>= 1) s += __shfl_down(s, st, 8);
    __shared__ float ah[32];
    if (lane == 0) ah[grp] = s + b_out[j];
    __syncthreads();
    if (tid < 8) {
        float a0 = ah[tid * 4 + 0], a1 = ah[tid * 4 + 1], a2 = ah[tid * 4 + 2], a3 = ah[tid * 4 + 3];
        out[tid * 4 + 0] = a0; out[tid * 4 + 1] = a1; out[tid * 4 + 2] = a2; out[tid * 4 + 3] = a3;
        float mx = fmaxf(fmaxf(a0, a1), fmaxf(a2, a3));
        float e0 = expf(a0 - mx), e1 = expf(a1 - mx), e2 = expf(a2 - mx), e3 = expf(a3 - mx);
        float sm = e0 + e1 + e2 + e3;
        out[32 + tid * 4 + 0] = e0 / sm; out[32 + tid * 4 + 1] = e1 / sm;
        out[32 + tid * 4 + 2] = e2 / sm; out[32 + tid * 4 + 3] = e3 / sm;
    }
    for (int i = tid; i < ROWS_; i += 256) {
        out[64 + i] = rem[i];
        out[64 + ROWS_ + i] = nup[i];
    }
}

// ---------------------------------------------------------------------------
extern "C" void kernel_launch(void* const* d_in, const int* in_sizes, int n_in,
                              void* d_out, int out_size, void* d_ws, size_t ws_size,
                              hipStream_t stream) {
    const int*   X     = (const int*)  d_in[0];
    const float* emb   = (const float*)d_in[1];
    const float* p_w   = (const float*)d_in[2];
    const float* p_b   = (const float*)d_in[3];
    const float* Wq    = (const float*)d_in[4];
    const float* Wk    = (const float*)d_in[5];
    const float* Wv    = (const float*)d_in[6];
    const float* Wo    = (const float*)d_in[7];
    const float* ln1_g = (const float*)d_in[8];
    const float* ln1_b = (const float*)d_in[9];
    const float* ln2_g = (const float*)d_in[10];
    const float* ln2_b = (const float*)d_in[11];
    const float* K1    = (const float*)d_in[12];
    const float* c1_b  = (const float*)d_in[13];
    const float* K2    = (const float*)d_in[14];
    const float* c2_b  = (const float*)d_in[15];
    const float* W_out = (const float*)d_in[16];
    const float* b_out = (const float*)d_in[17];

    char* ws = (char*)d_ws;
    size_t off = 0;
    auto alloc = [&](size_t bytes) { char* p = ws + off; off += (bytes + 255) & ~(size_t)255; return p; };

    float*    state  = (float*)alloc(NE_ * 4);
    float*    prev   = (float*)alloc(NE_ * 4);
    ushort_t* xn1h   = (ushort_t*)alloc(NE_ * 2);
    ushort_t* xn1l   = (ushort_t*)alloc(NE_ * 2);
    ushort_t* ctxh   = (ushort_t*)alloc(NE_ * 2);
    ushort_t* ctxl   = (ushort_t*)alloc(NE_ * 2);
    ushort_t* xn2ph  = (ushort_t*)alloc((size_t)B_ * LP_ * D_ * 2);
    ushort_t* xn2pl  = (ushort_t*)alloc((size_t)B_ * LP_ * D_ * 2);
    // union region (67.37 MB): [ qkv fp32 50.33 MB | Vth 8.39 | Vtl 8.39 ]
    // later aliased by h_hi|h_lo padded conv buffers
    char*     uni    = alloc((size_t)B_ * LP_ * FILT_ * 2 * 2);
    float*    qkv    = (float*)uni;
    ushort_t* Vth    = (ushort_t*)(uni + (size_t)ROWS_ * 3 * D_ * 4);
    ushort_t* Vtl    = Vth + (size_t)B_ * H_ * DKH_ * L_;
    ushort_t* hbh    = (ushort_t*)uni;
    ushort_t* hbl    = (ushort_t*)(uni + (size_t)B_ * LP_ * FILT_ * 2);
    float*    part   = (float*)alloc(2 * NE_ * 4);       // split-K partials (32 MB)
    ushort_t* WqkvTh = (ushort_t*)alloc((size_t)(3 * D_) * D_ * 2);
    ushort_t* WqkvTl = (ushort_t*)alloc((size_t)(3 * D_) * D_ * 2);
    ushort_t* WoTh   = (ushort_t*)alloc((size_t)D_ * D_ * 2);
    ushort_t* WoTl   = (ushort_t*)alloc((size_t)D_ * D_ * 2);
    ushort_t* K1Th   = (ushort_t*)alloc((size_t)FILT_ * (3 * D_) * 2);
    ushort_t* K1Tl   = (ushort_t*)alloc((size_t)FILT_ * (3 * D_) * 2);
    ushort_t* K2Th   = (ushort_t*)alloc((size_t)D_ * (3 * FILT_) * 2);
    ushort_t* K2Tl   = (ushort_t*)alloc((size_t)D_ * (3 * FILT_) * 2);
    float* timesig = (float*)alloc((size_t)L_ * D_ * 4);
    float* possig  = (float*)alloc((size_t)NLAYERS_ * D_ * 4);
    float* hp      = (float*)alloc(ROWS_ * 4);
    float* rem     = (float*)alloc(ROWS_ * 4);
    float* nup     = (float*)alloc(ROWS_ * 4);
    float* uw      = (float*)alloc(ROWS_ * 4);
    float* meanbuf = (float*)alloc(B_ * D_ * 4);

    hipMemsetAsync(prev, 0, NE_ * 4, stream);
    hipMemsetAsync(hp, 0, ROWS_ * 4, stream);
    hipMemsetAsync(rem, 0, ROWS_ * 4, stream);
    hipMemsetAsync(nup, 0, ROWS_ * 4, stream);

    // weight prep: transpose + split; fold q-scale 0.125 (exact pow2) into Wq
    transpose_split_kernel<<<dim3(32, 32), 256, 0, stream>>>(Wq, WqkvTh, WqkvTl, D_, D_, D_, 0, 0,       0.125f);
    transpose_split_kernel<<<dim3(32, 32), 256, 0, stream>>>(Wk, WqkvTh, WqkvTl, D_, D_, D_, 0, D_,      1.f);
    transpose_split_kernel<<<dim3(32, 32), 256, 0, stream>>>(Wv, WqkvTh, WqkvTl, D_, D_, D_, 0, 2 * D_,  1.f);
    transpose_split_kernel<<<dim3(32, 32), 256, 0, stream>>>(Wo, WoTh, WoTl, D_, D_, D_, 0, 0, 1.f);
    for (int t = 0; t < 3; ++t) {
        transpose_split_kernel<<<dim3(128, 32), 256, 0, stream>>>(
            K1 + (size_t)t * D_ * FILT_, K1Th, K1Tl, D_, FILT_, 3 * D_, t * D_, 0, 1.f);
        transpose_split_kernel<<<dim3(32, 128), 256, 0, stream>>>(
            K2 + (size_t)t * FILT_ * D_, K2Th, K2Tl, FILT_, D_, 3 * FILT_, t * FILT_, 0, 1.f);
    }
    sig_kernel<<<(L_ * D_) / 256, 256, 0, stream>>>(timesig, possig);

    embed_kernel<<<ROWS_, 256, 0, stream>>>(X, emb, state);

    dim3 gQKV(3 * D_ / 128, ROWS_ / 128);      // (24, 32)    128x128, 2 res/CU
    dim3 gWo(D_ / 64, ROWS_ / 128);            // (16, 32)    128x64,  3 blk/CU
    dim3 gC1(FILT_ / 128, ROWS_ / 128);        // (32, 32)    128x128, 2 res/CU
    dim3 gC2(D_ / 128, ROWS_ / 128, 2);        // (8, 32, 2)  128x128 split-K=2

    for (int t = 0; t < NLAYERS_; ++t) {
        add_sig_kernel<<<NE_ / 256, 256, 0, stream>>>(state, timesig, possig, t);
        act_kernel<<<ROWS_, 256, 0, stream>>>(state, p_w, p_b, hp, rem, nup, uw);
        ln_kernel<0><<<ROWS_, 256, 0, stream>>>(state, ln1_g, ln1_b, xn1h, xn1l);

        // qkv = xn @ [0.125*Wq | Wk | Wv]  (fp32 out)
        mfma_gemm_pipe<128,128,2,2, 2, 0,0,0,0,0, 1><<<gQKV, 256, 0, stream>>>(
            xn1h, xn1l, WqkvTh, WqkvTl, qkv, nullptr, nullptr, ROWS_, 3 * D_, D_);
        vt_kernel<<<dim3(L_ / 64, H_, B_), 256, 0, stream>>>(qkv, Vth, Vtl);
        fattn_kernel<<<dim3(L_ / 128, H_, B_), 256, 0, stream>>>(qkv, Vth, Vtl, ctxh, ctxl);

        // state += ctx @ Wo
        mfma_gemm_pipe<128,64,2,2, 3, 0,0,1,0,0, 1><<<gWo, 256, 0, stream>>>(
            ctxh, ctxl, WoTh, WoTl, state, nullptr, nullptr, ROWS_, D_, D_);

        // re-zero conv halos (h region aliases qkv/Vt — now dead)
        zero_halo_kernel<<<81920 / 256, 256, 0, stream>>>(xn2ph, xn2pl, hbh, hbl);

        ln_kernel<1><<<ROWS_, 256, 0, stream>>>(state, ln2_g, ln2_b, xn2ph, xn2pl);

        // h = relu(conv1(xn2) + c1_b)  -> padded split bf16
        mfma_gemm_pipe<128,128,2,2, 2, 1,10,3,1,1, 1><<<gC1, 256, 0, stream>>>(
            xn2ph, xn2pl, K1Th, K1Tl, hbh, hbl, c1_b, ROWS_, FILT_, 3 * D_);
        // conv2 partials (split-K=2), then fused reduce: state += sum + c2_b,
        // prev = state*uw + prev*(1-uw)
        mfma_gemm_pipe<128,128,2,2, 2, 1,12,0,0,0, 2><<<gC2, 256, 0, stream>>>(
            hbh, hbl, K2Th, K2Tl, part, nullptr, nullptr, ROWS_, D_, 3 * FILT_);
        reduce_k_kernel<<<(int)(NE_ / 4 / 256), 256, 0, stream>>>(part, c2_b, state, prev, uw);
    }

    mean_kernel<<<(B_ * D_) / 256, 256, 0, stream>>>(prev, meanbuf);
    final_kernel<<<1, 256, 0, stream>>>(meanbuf, W_out, b_out, rem, nup, (float*)d_out);
}

// Round 5
// 5134.547 us; speedup vs baseline: 1.3088x; 1.0647x over previous
//
#include <hip/hip_runtime.h>
#include <math.h>

// Problem constants
#define B_   8
#define L_   512
#define LP_  514                 // padded rows per batch (halo row each side)
#define D_   1024
#define H_   16
#define DKH_ 64
#define FILT_ 4096
#define NLAYERS_ 6
#define ROWS_ (B_*L_)            // 4096
#define NE_   ((size_t)ROWS_*D_) // 4194304 elems per (B,L,D) tensor

typedef unsigned short ushort_t;
typedef unsigned int uint_t;
using short8 = __attribute__((ext_vector_type(8))) short;
using f32x4  = __attribute__((ext_vector_type(4))) float;

typedef const __attribute__((address_space(1))) void* gas_ptr;
typedef __attribute__((address_space(3))) void* las_ptr;
#define GLOAD_LDS16(g, s) __builtin_amdgcn_global_load_lds((gas_ptr)(g), (las_ptr)(s), 16, 0, 0)

__device__ __forceinline__ float bf2f(ushort_t h) { return __uint_as_float((uint_t)h << 16); }
__device__ __forceinline__ ushort_t f2bf(float f) {
    uint_t u = __float_as_uint(f);
    u = (u + 0x7FFFu + ((u >> 16) & 1u)) >> 16;   // RNE
    return (ushort_t)u;
}

// ---------------------------------------------------------------------------
__global__ __launch_bounds__(256) void embed_kernel(const int* __restrict__ X,
                                                    const float* __restrict__ emb,
                                                    float* __restrict__ state) {
    int row = blockIdx.x;
    int tok = X[row];
    const float4* src = (const float4*)(emb + (size_t)tok * D_);
    float4* dst = (float4*)(state + (size_t)row * D_);
    dst[threadIdx.x] = src[threadIdx.x];
}

// ---------------------------------------------------------------------------
// Precompute TIME_SIG (L x D) and POS_SIG (NLAYERS x D) once per launch.
__global__ __launch_bounds__(256) void sig_kernel(float* __restrict__ timesig,
                                                  float* __restrict__ possig) {
    int idx = blockIdx.x * 256 + threadIdx.x;      // L_*D_ = 524288
    int c = idx & (D_ - 1);
    int l = idx >> 10;
    const float log_inc = 0.0180241494559220821f;  // log(10000)/511
    int j = c & 511;
    float inv = expf(-log_inc * (float)j);
    timesig[idx] = (c < 512) ? sinf((float)l * inv) : cosf((float)l * inv);
    if (l < NLAYERS_)
        possig[idx] = (c < 512) ? sinf((float)l * inv) : cosf((float)l * inv);
}

// state += TIME_SIG[l,c] + POS_SIG[t,c]
__global__ __launch_bounds__(256) void add_sig_kernel(float* __restrict__ state,
                                                      const float* __restrict__ timesig,
                                                      const float* __restrict__ possig,
                                                      int layer_t) {
    int idx = blockIdx.x * 256 + threadIdx.x;
    int c = idx & (D_ - 1);
    int tl = idx & (L_ * D_ - 1);
    state[idx] += timesig[tl] + possig[layer_t * D_ + c];
}

// ---------------------------------------------------------------------------
__global__ __launch_bounds__(256) void act_kernel(const float* __restrict__ state,
                                                  const float* __restrict__ p_w,
                                                  const float* __restrict__ p_b,
                                                  float* __restrict__ hp, float* __restrict__ rem,
                                                  float* __restrict__ nup, float* __restrict__ uw) {
    int row = blockIdx.x;
    const float* x = state + (size_t)row * D_;
    float s = 0.f;
    for (int i = threadIdx.x; i < D_; i += 256) s += x[i] * p_w[i];
    __shared__ float red[256];
    red[threadIdx.x] = s; __syncthreads();
    for (int st = 128; st > 0; st >>= 1) {
        if (threadIdx.x < st) red[threadIdx.x] += red[threadIdx.x + st];
        __syncthreads();
    }
    if (threadIdx.x == 0) {
        float p = 1.f / (1.f + expf(-(red[0] + p_b[0])));
        float h = hp[row], r = rem[row], n = nup[row];
        float still = (h < 1.0f) ? 1.f : 0.f;
        float add = h + p * still;
        float nh     = (add > 0.9f) ? still : 0.f;
        float still2 = (add <= 0.9f) ? still : 0.f;
        h += p * still2;
        r += nh * (1.f - h);
        h += nh * r;
        n += still2 + nh;
        hp[row] = h; rem[row] = r; nup[row] = n;
        uw[row] = p * still2 + nh * r;
    }
}

// ---------------------------------------------------------------------------
// LayerNorm (ddof=1), fp32 in, split bf16 hi/lo out.  OUT_PAD: padded layout.
template<int OUT_PAD>
__global__ __launch_bounds__(256) void ln_kernel(const float* __restrict__ x,
                                                 const float* __restrict__ g,
                                                 const float* __restrict__ b,
                                                 ushort_t* __restrict__ yh,
                                                 ushort_t* __restrict__ yl) {
    int row = blockIdx.x;
    const float4* xr = (const float4*)(x + (size_t)row * D_);
    float4 v = xr[threadIdx.x];
    __shared__ float red[256];
    float s = v.x + v.y + v.z + v.w;
    red[threadIdx.x] = s; __syncthreads();
    for (int st = 128; st > 0; st >>= 1) { if (threadIdx.x < st) red[threadIdx.x] += red[threadIdx.x + st]; __syncthreads(); }
    float mu = red[0] * (1.f / D_);
    __syncthreads();
    float dx0 = v.x - mu, dx1 = v.y - mu, dx2 = v.z - mu, dx3 = v.w - mu;
    red[threadIdx.x] = dx0*dx0 + dx1*dx1 + dx2*dx2 + dx3*dx3; __syncthreads();
    for (int st = 128; st > 0; st >>= 1) { if (threadIdx.x < st) red[threadIdx.x] += red[threadIdx.x + st]; __syncthreads(); }
    float sd = sqrtf(red[0] * (1.f / (D_ - 1)));
    float inv = 1.f / (sd + 1e-6f);
    const float4* g4 = (const float4*)g;
    const float4* b4 = (const float4*)b;
    float4 gv = g4[threadIdx.x], bv = b4[threadIdx.x];
    float o0 = gv.x * dx0 * inv + bv.x;
    float o1 = gv.y * dx1 * inv + bv.y;
    float o2 = gv.z * dx2 * inv + bv.z;
    float o3 = gv.w * dx3 * inv + bv.w;
    int orow = OUT_PAD ? ((row >> 9) * LP_ + (row & (L_ - 1)) + 1) : row;
    ushort4 oh, ol;
    oh.x = f2bf(o0); ol.x = f2bf(o0 - bf2f(oh.x));
    oh.y = f2bf(o1); ol.y = f2bf(o1 - bf2f(oh.y));
    oh.z = f2bf(o2); ol.z = f2bf(o2 - bf2f(oh.z));
    oh.w = f2bf(o3); ol.w = f2bf(o3 - bf2f(oh.w));
    ((ushort4*)(yh + (size_t)orow * D_))[threadIdx.x] = oh;
    ((ushort4*)(yl + (size_t)orow * D_))[threadIdx.x] = ol;
}

// ---------------------------------------------------------------------------
// Transpose + split: dst[nbase+c][kbase+r] = split(scale * src[r][c])
__global__ __launch_bounds__(256) void transpose_split_kernel(const float* __restrict__ src,
                                                              ushort_t* __restrict__ dhi,
                                                              ushort_t* __restrict__ dlo,
                                                              int R, int C, int dstride,
                                                              int kbase, int nbase, float scale) {
    __shared__ float tile[32][33];
    int tx = threadIdx.x & 31, ty = threadIdx.x >> 5;   // 32 x 8
    int r0 = blockIdx.y * 32, c0 = blockIdx.x * 32;
#pragma unroll
    for (int i = 0; i < 4; ++i)
        tile[ty + i * 8][tx] = src[(size_t)(r0 + ty + i * 8) * C + c0 + tx] * scale;
    __syncthreads();
#pragma unroll
    for (int i = 0; i < 4; ++i) {
        int c = c0 + ty + i * 8;
        float val = tile[tx][ty + i * 8];
        ushort_t hi = f2bf(val);
        ushort_t lo = f2bf(val - bf2f(hi));
        size_t idx = (size_t)(nbase + c) * dstride + kbase + r0 + tx;
        dhi[idx] = hi; dlo[idx] = lo;
    }
}

// ---------------------------------------------------------------------------
// Zero halo rows of all four padded activation buffers
__global__ __launch_bounds__(256) void zero_halo_kernel(ushort_t* __restrict__ xh,
                                                        ushort_t* __restrict__ xl,
                                                        ushort_t* __restrict__ hh,
                                                        ushort_t* __restrict__ hl) {
    int idx = blockIdx.x * 256 + threadIdx.x;          // 81920 total
    if (idx < 16384) {
        int b = idx >> 11, r = (idx >> 10) & 1, c = idx & 1023;
        size_t o = ((size_t)b * LP_ + r * (LP_ - 1)) * D_ + c;
        xh[o] = 0; xl[o] = 0;
    } else {
        int j = idx - 16384;
        int b = j >> 13, r = (j >> 12) & 1, c = j & 4095;
        size_t o = ((size_t)b * LP_ + r * (LP_ - 1)) * FILT_ + c;
        hh[o] = 0; hl[o] = 0;
    }
}

// ---------------------------------------------------------------------------
// Pipelined bf16x3 MFMA GEMM: C = epi( A @ Bt^T ), A ~ Ahi+Alo, B ~ Bhi+Blo.
// BK=32, double-buffered LDS, counted vmcnt (T3/T4): stage(i+1) issued first,
// then s_waitcnt vmcnt(G) -> only stage(i) must have landed; stage(i+1) stays
// in flight across both barriers.  B1 = buf valid; B2 = reads done block-wide.
// Wave tile geometry is the LDS-read lever: reads/MFMA ~ (WM+WN)/(WM*WN).
//   - 2x4 waves of 128x64 (256^2 block, 512 thr, 128 KiB LDS, 1 blk/CU):
//     ratio 2.47 -- m201-proven geometry.  For the big conv GEMMs.
//   - 2x2 waves of 64x64 (128^2, 256 thr, 64 KiB, 2 blk/CU): QKV.
// Staging addresses are LINEAR in k0 (im2col over contiguous padded rows:
// goff = rowbase<<SH + k0 + gk) -> per-thread bases hoisted out of the loop.
// LDS chunk layout: 16B chunk q = p*8+s holds global (row=2p+(cs>>2),
// kchunk=cs&3), cs = s^(p&7) -> ds_read_b128 conflict-free, linear gload dest.
// OUT_MODE: 0=f32 store (+z-slice for SPLITK), 1=f32 accumulate,
// 3=split bf16 store padded.
template<int BM, int BN, int WAVES_M, int WAVES_N, int OCC, int PAD,
         int DIN_SHIFT, int OUT_MODE, int RELU, int HAS_BIAS, int SPLITK>
__global__ __launch_bounds__(WAVES_M*WAVES_N*64, OCC)
void mfma_gemm_pipe(const ushort_t* __restrict__ Ahi,
                    const ushort_t* __restrict__ Alo,
                    const ushort_t* __restrict__ Bhi,
                    const ushort_t* __restrict__ Blo,
                    void* __restrict__ C, ushort_t* __restrict__ Clo,
                    const float* __restrict__ bias,
                    int M, int N, int K) {
    constexpr int NW = WAVES_M * WAVES_N;
    constexpr int NT = NW * 64;
    constexpr int WM = BM / WAVES_M;
    constexpr int WN = BN / WAVES_N;
    constexpr int MF = WM / 16;
    constexpr int NF = WN / 16;
    constexpr int MH = MF / 2;
    constexpr int AITER = (BM * 4) / NT;   // A 16B-chunks per thread per tile
    constexpr int BITER = (BN * 4) / NT;
    constexpr int G = 2 * (AITER + BITER); // gload_lds per thread per stage
    static_assert(G == 6 || G == 8, "vmcnt literal table");
    __shared__ __align__(16) ushort_t AsH[2][BM * 32];
    __shared__ __align__(16) ushort_t AsL[2][BM * 32];
    __shared__ __align__(16) ushort_t BsH[2][BN * 32];
    __shared__ __align__(16) ushort_t BsL[2][BN * 32];
    const int tid = threadIdx.x;
    const int w = tid >> 6, l = tid & 63;
    const int lm = l & 15, lc = l >> 4;
    // GROUP_M=8 swizzle (gridDim.y multiple of 8)
    const int bid = blockIdx.y * gridDim.x + blockIdx.x;
    const int stripe = 8 * gridDim.x;
    const int m0 = ((bid / stripe) * 8 + (bid & 7)) * BM;
    const int n0 = ((bid % stripe) >> 3) * BN;
    const int wm = (w / WAVES_N) * WM;
    const int wn = (w % WAVES_N) * WN;
    const int kch  = K / SPLITK;
    const int kbeg = (SPLITK > 1) ? blockIdx.z * kch : 0;
    const int kend = kbeg + kch;

    f32x4 acc[MF][NF];
#pragma unroll
    for (int i = 0; i < MF; ++i)
#pragma unroll
        for (int j = 0; j < NF; ++j) acc[i][j] = (f32x4)0.f;

    // ---- hoisted per-thread staging bases (goff = base + k0; lds = off) ----
    size_t baseA[AITER], baseB[BITER];
    int ldsA[AITER], ldsB[BITER];
#pragma unroll
    for (int i = 0; i < AITER; ++i) {
        int q = i * NT + tid;
        int p = q >> 3, s = q & 7;
        int cs = s ^ (p & 7);
        int grow = p * 2 + (cs >> 2);
        int gk = (cs & 3) * 8;
        if (PAD) {
            int row = m0 + grow;
            int rg = (row >> 9) * LP_ + (row & (L_ - 1));   // tap-0 padded row
            baseA[i] = ((size_t)rg << DIN_SHIFT) + gk;      // + k0 is linear
        } else {
            baseA[i] = (size_t)(m0 + grow) * K + gk;
        }
        ldsA[i] = q * 8;
    }
#pragma unroll
    for (int i = 0; i < BITER; ++i) {
        int q = i * NT + tid;
        int p = q >> 3, s = q & 7;
        int cs = s ^ (p & 7);
        int grow = p * 2 + (cs >> 2);
        int gk = (cs & 3) * 8;
        baseB[i] = (size_t)(n0 + grow) * K + gk;
        ldsB[i] = q * 8;
    }

    auto stage = [&](int k0, int buf) {
#pragma unroll
        for (int i = 0; i < AITER; ++i) {
            size_t goff = baseA[i] + k0;
            GLOAD_LDS16(Ahi + goff, &AsH[buf][ldsA[i]]);
            GLOAD_LDS16(Alo + goff, &AsL[buf][ldsA[i]]);
        }
#pragma unroll
        for (int i = 0; i < BITER; ++i) {
            size_t goff = baseB[i] + k0;
            GLOAD_LDS16(Bhi + goff, &BsH[buf][ldsB[i]]);
            GLOAD_LDS16(Blo + goff, &BsL[buf][ldsB[i]]);
        }
    };

    // swizzled ds_read of one short8 fragment: row r, k-chunk c
    auto ldf = [&](const ushort_t* base, int r, int c) -> short8 {
        int p = r >> 1;
        int s = (((r & 1) << 2) | c) ^ (p & 7);
        return *(const short8*)(base + (size_t)((p << 3) + s) * 8);
    };

    int cur = 0;
    stage(kbeg, 0);

    for (int k0 = kbeg; k0 < kend; k0 += 32) {
        // issue next tile's staging first, then COUNTED wait: only the
        // previous stage (G oldest loads) must have landed.
        if (k0 + 32 < kend) {
            stage(k0 + 32, cur ^ 1);
            if constexpr (G == 6) asm volatile("s_waitcnt vmcnt(6)" ::: "memory");
            else                  asm volatile("s_waitcnt vmcnt(8)" ::: "memory");
        } else {
            asm volatile("s_waitcnt vmcnt(0)" ::: "memory");
        }
        __builtin_amdgcn_s_barrier();      // B1: buf[cur] valid for all waves

        short8 bfh[NF], bfl[NF];
#pragma unroll
        for (int j = 0; j < NF; ++j) {
            int rB = wn + j * 16 + lm;
            bfh[j] = ldf(&BsH[cur][0], rB, lc);
            bfl[j] = ldf(&BsL[cur][0], rB, lc);
        }
#pragma unroll
        for (int h = 0; h < 2; ++h) {
            short8 afh[MH], afl[MH];
#pragma unroll
            for (int i = 0; i < MH; ++i) {
                int rA = wm + (h * MH + i) * 16 + lm;
                afh[i] = ldf(&AsH[cur][0], rA, lc);
                afl[i] = ldf(&AsL[cur][0], rA, lc);
            }
            __builtin_amdgcn_s_setprio(1);
#pragma unroll
            for (int i = 0; i < MH; ++i)
#pragma unroll
                for (int j = 0; j < NF; ++j) {
                    f32x4 a = acc[h * MH + i][j];
                    a = __builtin_amdgcn_mfma_f32_16x16x32_bf16(afh[i], bfh[j], a, 0, 0, 0);
                    a = __builtin_amdgcn_mfma_f32_16x16x32_bf16(afl[i], bfh[j], a, 0, 0, 0);
                    a = __builtin_amdgcn_mfma_f32_16x16x32_bf16(afh[i], bfl[j], a, 0, 0, 0);
                    acc[h * MH + i][j] = a;
                }
            __builtin_amdgcn_s_setprio(0);
        }
        __builtin_amdgcn_s_barrier();      // B2: reads of buf[cur] done block-wide
        cur ^= 1;
    }

    // epilogue.  C/D layout: col = lane&15, row = (lane>>4)*4 + reg
    const size_t zoff = (size_t)blockIdx.z * (size_t)M * (size_t)N;
#pragma unroll
    for (int i = 0; i < MF; ++i) {
#pragma unroll
        for (int j = 0; j < NF; ++j) {
#pragma unroll
            for (int r = 0; r < 4; ++r) {
                int row = m0 + wm + i * 16 + lc * 4 + r;
                int col = n0 + wn + j * 16 + lm;
                float v = acc[i][j][r];
                if (HAS_BIAS) v += bias[col];
                if (RELU) v = fmaxf(v, 0.f);
                size_t off;
                if (OUT_MODE == 3) off = (size_t)((row >> 9) * LP_ + (row & (L_ - 1)) + 1) * N + col;
                else               off = (size_t)row * N + col;
                if (OUT_MODE == 0) {
                    ((float*)C)[zoff + off] = v;
                } else if (OUT_MODE == 1) {
                    float* Cf = (float*)C;
                    Cf[off] += v;
                } else {
                    ushort_t hi = f2bf(v);
                    ((ushort_t*)C)[off] = hi;
                    Clo[off] = f2bf(v - bf2f(hi));
                }
            }
        }
    }
}

// ---------------------------------------------------------------------------
// Split-K reduce for conv2: state += sum(parts) + c2_b; prev blend fused.
__global__ __launch_bounds__(256) void reduce_k_kernel(const float* __restrict__ part,
                                                       const float* __restrict__ bias,
                                                       float* __restrict__ state,
                                                       float* __restrict__ prev,
                                                       const float* __restrict__ uw) {
    int idx = blockIdx.x * 256 + threadIdx.x;      // NE_/4 float4 elems
    int row = idx >> 8;                            // 256 float4 per row (N=1024)
    int c4  = idx & 255;
    float4 acc = ((const float4*)part)[idx];
#pragma unroll
    for (int r = 1; r < 4; ++r) {
        float4 p = ((const float4*)part)[r * (NE_ >> 2) + idx];
        acc.x += p.x; acc.y += p.y; acc.z += p.z; acc.w += p.w;
    }
    float4 bv = ((const float4*)bias)[c4];
    float4 st = ((float4*)state)[idx];
    float4 pv = ((float4*)prev)[idx];
    float u = uw[row];
    float4 s;
    s.x = st.x + acc.x + bv.x;
    s.y = st.y + acc.y + bv.y;
    s.z = st.z + acc.z + bv.z;
    s.w = st.w + acc.w + bv.w;
    ((float4*)state)[idx] = s;
    pv.x = s.x * u + pv.x * (1.f - u);
    pv.y = s.y * u + pv.y * (1.f - u);
    pv.z = s.z * u + pv.z * (1.f - u);
    pv.w = s.w * u + pv.w * (1.f - u);
    ((float4*)prev)[idx] = pv;
}

// ---------------------------------------------------------------------------
// V transpose+split: Vt[b,h,d,key] (hi/lo bf16) from qkv fp32 V-section.
__global__ __launch_bounds__(256) void vt_kernel(const float* __restrict__ qkv,
                                                 ushort_t* __restrict__ Vth,
                                                 ushort_t* __restrict__ Vtl) {
    __shared__ float t[64][65];
    int kt = blockIdx.x, h = blockIdx.y, b = blockIdx.z;
    int tx = threadIdx.x & 63, ty = threadIdx.x >> 6;  // 64 x 4
#pragma unroll
    for (int i = 0; i < 16; ++i) {
        int r = ty + i * 4;            // key within tile
        t[r][tx] = qkv[(size_t)(b * L_ + kt * 64 + r) * (3 * D_) + 2 * D_ + h * DKH_ + tx];
    }
    __syncthreads();
#pragma unroll
    for (int i = 0; i < 16; ++i) {
        int d = ty + i * 4;
        float v = t[tx][d];            // key=tx, dim=d
        size_t o = ((size_t)((b * H_ + h) * DKH_ + d)) * L_ + kt * 64 + tx;
        ushort_t hj = f2bf(v);
        Vth[o] = hj; Vtl[o] = f2bf(v - bf2f(hj));
    }
}

// ---------------------------------------------------------------------------
// Flash MFMA attention, bf16x3 split precision (~fp32), online softmax.
__global__ __launch_bounds__(256, 2) void fattn_kernel(const float* __restrict__ qkv,
                                                       const ushort_t* __restrict__ Vth,
                                                       const ushort_t* __restrict__ Vtl,
                                                       ushort_t* __restrict__ ctxh,
                                                       ushort_t* __restrict__ ctxl) {
    __shared__ __align__(16) ushort_t Ph[4][32 * 136];
    __shared__ __align__(16) ushort_t Pl[4][32 * 136];
    int qt = blockIdx.x, h = blockIdx.y, b = blockIdx.z;
    int w = threadIdx.x >> 6, l = threadIdx.x & 63;
    int lm = l & 15, lq = l >> 4;
    int q0 = qt * 128 + w * 32;

    short8 qfh[2][2], qfl[2][2];
#pragma unroll
    for (int mt = 0; mt < 2; ++mt)
#pragma unroll
        for (int ks = 0; ks < 2; ++ks) {
            const float* qp = qkv + (size_t)(b * L_ + q0 + mt * 16 + lm) * (3 * D_)
                              + h * DKH_ + ks * 32 + lq * 8;
            short8 hi, lo;
#pragma unroll
            for (int j = 0; j < 8; ++j) {
                float x = qp[j];
                ushort_t hj = f2bf(x);
                hi[j] = (short)hj;
                lo[j] = (short)f2bf(x - bf2f(hj));
            }
            qfh[mt][ks] = hi; qfl[mt][ks] = lo;
        }

    float mrow[2][4], lrow[2][4];
    f32x4 oacc[2][4];
#pragma unroll
    for (int mt = 0; mt < 2; ++mt)
#pragma unroll
        for (int r = 0; r < 4; ++r) { mrow[mt][r] = -3.0e38f; lrow[mt][r] = 0.f; }
#pragma unroll
    for (int mt = 0; mt < 2; ++mt)
#pragma unroll
        for (int nt = 0; nt < 4; ++nt) oacc[mt][nt] = (f32x4)0.f;

    for (int c = 0; c < 4; ++c) {           // key chunks of 128
        f32x4 s[2][8];
#pragma unroll
        for (int mt = 0; mt < 2; ++mt)
#pragma unroll
            for (int nt = 0; nt < 8; ++nt) s[mt][nt] = (f32x4)0.f;

#pragma unroll
        for (int nt = 0; nt < 8; ++nt) {
#pragma unroll
            for (int ks = 0; ks < 2; ++ks) {
                const float* kp = qkv + (size_t)(b * L_ + c * 128 + nt * 16 + lm) * (3 * D_)
                                  + D_ + h * DKH_ + ks * 32 + lq * 8;
                short8 kh, kl;
#pragma unroll
                for (int j = 0; j < 8; ++j) {
                    float x = kp[j];
                    ushort_t hj = f2bf(x);
                    kh[j] = (short)hj;
                    kl[j] = (short)f2bf(x - bf2f(hj));
                }
#pragma unroll
                for (int mt = 0; mt < 2; ++mt) {
                    s[mt][nt] = __builtin_amdgcn_mfma_f32_16x16x32_bf16(qfh[mt][ks], kh, s[mt][nt], 0, 0, 0);
                    s[mt][nt] = __builtin_amdgcn_mfma_f32_16x16x32_bf16(qfl[mt][ks], kh, s[mt][nt], 0, 0, 0);
                    s[mt][nt] = __builtin_amdgcn_mfma_f32_16x16x32_bf16(qfh[mt][ks], kl, s[mt][nt], 0, 0, 0);
                }
            }
        }

#pragma unroll
        for (int mt = 0; mt < 2; ++mt) {
#pragma unroll
            for (int r = 0; r < 4; ++r) {
                float cm = s[mt][0][r];
#pragma unroll
                for (int nt = 1; nt < 8; ++nt) cm = fmaxf(cm, s[mt][nt][r]);
                cm = fmaxf(cm, __shfl_xor(cm, 1));
                cm = fmaxf(cm, __shfl_xor(cm, 2));
                cm = fmaxf(cm, __shfl_xor(cm, 4));
                cm = fmaxf(cm, __shfl_xor(cm, 8));
                float mnew = fmaxf(mrow[mt][r], cm);
                float alpha = expf(mrow[mt][r] - mnew);
                mrow[mt][r] = mnew;
                float ps = 0.f;
                int rw = mt * 16 + lq * 4 + r;
#pragma unroll
                for (int nt = 0; nt < 8; ++nt) {
                    float p = expf(s[mt][nt][r] - mnew);
                    ps += p;
                    ushort_t hj = f2bf(p);
                    int cl = nt * 16 + lm;
                    Ph[w][rw * 136 + cl] = hj;
                    Pl[w][rw * 136 + cl] = f2bf(p - bf2f(hj));
                }
                ps += __shfl_xor(ps, 1);
                ps += __shfl_xor(ps, 2);
                ps += __shfl_xor(ps, 4);
                ps += __shfl_xor(ps, 8);
                lrow[mt][r] = lrow[mt][r] * alpha + ps;
#pragma unroll
                for (int nt = 0; nt < 4; ++nt) oacc[mt][nt][r] *= alpha;
            }
        }
        asm volatile("s_waitcnt lgkmcnt(0)" ::: "memory");

#pragma unroll
        for (int ks = 0; ks < 4; ++ks) {
            short8 pah[2], pal[2];
#pragma unroll
            for (int mt = 0; mt < 2; ++mt) {
                pah[mt] = *(const short8*)&Ph[w][(mt * 16 + lm) * 136 + ks * 32 + lq * 8];
                pal[mt] = *(const short8*)&Pl[w][(mt * 16 + lm) * 136 + ks * 32 + lq * 8];
            }
#pragma unroll
            for (int nt = 0; nt < 4; ++nt) {
                size_t vo = ((size_t)((b * H_ + h) * DKH_ + nt * 16 + lm)) * L_ + c * 128 + ks * 32 + lq * 8;
                short8 vh = *(const short8*)(Vth + vo);
                short8 vl = *(const short8*)(Vtl + vo);
#pragma unroll
                for (int mt = 0; mt < 2; ++mt) {
                    oacc[mt][nt] = __builtin_amdgcn_mfma_f32_16x16x32_bf16(pah[mt], vh, oacc[mt][nt], 0, 0, 0);
                    oacc[mt][nt] = __builtin_amdgcn_mfma_f32_16x16x32_bf16(pal[mt], vh, oacc[mt][nt], 0, 0, 0);
                    oacc[mt][nt] = __builtin_amdgcn_mfma_f32_16x16x32_bf16(pah[mt], vl, oacc[mt][nt], 0, 0, 0);
                }
            }
        }
        asm volatile("s_waitcnt lgkmcnt(0)" ::: "memory");
    }

#pragma unroll
    for (int mt = 0; mt < 2; ++mt) {
#pragma unroll
        for (int nt = 0; nt < 4; ++nt) {
#pragma unroll
            for (int r = 0; r < 4; ++r) {
                float v = oacc[mt][nt][r] / lrow[mt][r];
                int rowg = b * L_ + qt * 128 + w * 32 + mt * 16 + lq * 4 + r;
                int colg = h * DKH_ + nt * 16 + lm;
                size_t o = (size_t)rowg * D_ + colg;
                ushort_t hj = f2bf(v);
                ctxh[o] = hj;
                ctxl[o] = f2bf(v - bf2f(hj));
            }
        }
    }
}

// ---------------------------------------------------------------------------
__global__ __launch_bounds__(256) void mean_kernel(const float* __restrict__ prev,
                                                   float* __restrict__ meanbuf) {
    int idx = blockIdx.x * 256 + threadIdx.x;  // 8192
    int b = idx >> 10, d = idx & (D_ - 1);
    float s = 0.f;
    for (int l = 0; l < L_; ++l) s += prev[((size_t)(b * L_ + l) << 10) + d];
    meanbuf[idx] = s * (1.f / L_);
}

// ---------------------------------------------------------------------------
__global__ __launch_bounds__(256) void final_kernel(const float* __restrict__ meanbuf,
                                                    const float* __restrict__ W_out,
                                                    const float* __restrict__ b_out,
                                                    const float* __restrict__ rem,
                                                    const float* __restrict__ nup,
                                                    float* __restrict__ out) {
    int tid = threadIdx.x;
    int grp = tid >> 3;
    int lane = tid & 7;
    int b = grp >> 2, j = grp & 3;
    float s = 0.f;
    for (int d2 = lane; d2 < D_; d2 += 8) s += meanbuf[b * D_ + d2] * W_out[d2 * 4 + j];
    for (int st = 4; st >= 1; st >>= 1) s += __shfl_down(s, st, 8);
    __shared__ float ah[32];
    if (lane == 0) ah[grp] = s + b_out[j];
    __syncthreads();
    if (tid < 8) {
        float a0 = ah[tid * 4 + 0], a1 = ah[tid * 4 + 1], a2 = ah[tid * 4 + 2], a3 = ah[tid * 4 + 3];
        out[tid * 4 + 0] = a0; out[tid * 4 + 1] = a1; out[tid * 4 + 2] = a2; out[tid * 4 + 3] = a3;
        float mx = fmaxf(fmaxf(a0, a1), fmaxf(a2, a3));
        float e0 = expf(a0 - mx), e1 = expf(a1 - mx), e2 = expf(a2 - mx), e3 = expf(a3 - mx);
        float sm = e0 + e1 + e2 + e3;
        out[32 + tid * 4 + 0] = e0 / sm; out[32 + tid * 4 + 1] = e1 / sm;
        out[32 + tid * 4 + 2] = e2 / sm; out[32 + tid * 4 + 3] = e3 / sm;
    }
    for (int i = tid; i < ROWS_; i += 256) {
        out[64 + i] = rem[i];
        out[64 + ROWS_ + i] = nup[i];
    }
}

// ---------------------------------------------------------------------------
extern "C" void kernel_launch(void* const* d_in, const int* in_sizes, int n_in,
                              void* d_out, int out_size, void* d_ws, size_t ws_size,
                              hipStream_t stream) {
    const int*   X     = (const int*)  d_in[0];
    const float* emb   = (const float*)d_in[1];
    const float* p_w   = (const float*)d_in[2];
    const float* p_b   = (const float*)d_in[3];
    const float* Wq    = (const float*)d_in[4];
    const float* Wk    = (const float*)d_in[5];
    const float* Wv    = (const float*)d_in[6];
    const float* Wo    = (const float*)d_in[7];
    const float* ln1_g = (const float*)d_in[8];
    const float* ln1_b = (const float*)d_in[9];
    const float* ln2_g = (const float*)d_in[10];
    const float* ln2_b = (const float*)d_in[11];
    const float* K1    = (const float*)d_in[12];
    const float* c1_b  = (const float*)d_in[13];
    const float* K2    = (const float*)d_in[14];
    const float* c2_b  = (const float*)d_in[15];
    const float* W_out = (const float*)d_in[16];
    const float* b_out = (const float*)d_in[17];

    char* ws = (char*)d_ws;
    size_t off = 0;
    auto alloc = [&](size_t bytes) { char* p = ws + off; off += (bytes + 255) & ~(size_t)255; return p; };

    float*    state  = (float*)alloc(NE_ * 4);
    float*    prev   = (float*)alloc(NE_ * 4);
    ushort_t* xn1h   = (ushort_t*)alloc(NE_ * 2);
    ushort_t* xn1l   = (ushort_t*)alloc(NE_ * 2);
    ushort_t* ctxh   = (ushort_t*)alloc(NE_ * 2);
    ushort_t* ctxl   = (ushort_t*)alloc(NE_ * 2);
    ushort_t* xn2ph  = (ushort_t*)alloc((size_t)B_ * LP_ * D_ * 2);
    ushort_t* xn2pl  = (ushort_t*)alloc((size_t)B_ * LP_ * D_ * 2);
    // union region (67.37 MB): [ qkv fp32 50.33 MB | Vth 8.39 | Vtl 8.39 ]
    // later aliased by h_hi|h_lo padded conv buffers
    char*     uni    = alloc((size_t)B_ * LP_ * FILT_ * 2 * 2);
    float*    qkv    = (float*)uni;
    ushort_t* Vth    = (ushort_t*)(uni + (size_t)ROWS_ * 3 * D_ * 4);
    ushort_t* Vtl    = Vth + (size_t)B_ * H_ * DKH_ * L_;
    ushort_t* hbh    = (ushort_t*)uni;
    ushort_t* hbl    = (ushort_t*)(uni + (size_t)B_ * LP_ * FILT_ * 2);
    float*    part   = (float*)alloc(4 * NE_ * 4);       // split-K partials (64 MB)
    ushort_t* WqkvTh = (ushort_t*)alloc((size_t)(3 * D_) * D_ * 2);
    ushort_t* WqkvTl = (ushort_t*)alloc((size_t)(3 * D_) * D_ * 2);
    ushort_t* WoTh   = (ushort_t*)alloc((size_t)D_ * D_ * 2);
    ushort_t* WoTl   = (ushort_t*)alloc((size_t)D_ * D_ * 2);
    ushort_t* K1Th   = (ushort_t*)alloc((size_t)FILT_ * (3 * D_) * 2);
    ushort_t* K1Tl   = (ushort_t*)alloc((size_t)FILT_ * (3 * D_) * 2);
    ushort_t* K2Th   = (ushort_t*)alloc((size_t)D_ * (3 * FILT_) * 2);
    ushort_t* K2Tl   = (ushort_t*)alloc((size_t)D_ * (3 * FILT_) * 2);
    float* timesig = (float*)alloc((size_t)L_ * D_ * 4);
    float* possig  = (float*)alloc((size_t)NLAYERS_ * D_ * 4);
    float* hp      = (float*)alloc(ROWS_ * 4);
    float* rem     = (float*)alloc(ROWS_ * 4);
    float* nup     = (float*)alloc(ROWS_ * 4);
    float* uw      = (float*)alloc(ROWS_ * 4);
    float* meanbuf = (float*)alloc(B_ * D_ * 4);

    hipMemsetAsync(prev, 0, NE_ * 4, stream);
    hipMemsetAsync(hp, 0, ROWS_ * 4, stream);
    hipMemsetAsync(rem, 0, ROWS_ * 4, stream);
    hipMemsetAsync(nup, 0, ROWS_ * 4, stream);

    // weight prep: transpose + split; fold q-scale 0.125 (exact pow2) into Wq
    transpose_split_kernel<<<dim3(32, 32), 256, 0, stream>>>(Wq, WqkvTh, WqkvTl, D_, D_, D_, 0, 0,       0.125f);
    transpose_split_kernel<<<dim3(32, 32), 256, 0, stream>>>(Wk, WqkvTh, WqkvTl, D_, D_, D_, 0, D_,      1.f);
    transpose_split_kernel<<<dim3(32, 32), 256, 0, stream>>>(Wv, WqkvTh, WqkvTl, D_, D_, D_, 0, 2 * D_,  1.f);
    transpose_split_kernel<<<dim3(32, 32), 256, 0, stream>>>(Wo, WoTh, WoTl, D_, D_, D_, 0, 0, 1.f);
    for (int t = 0; t < 3; ++t) {
        transpose_split_kernel<<<dim3(128, 32), 256, 0, stream>>>(
            K1 + (size_t)t * D_ * FILT_, K1Th, K1Tl, D_, FILT_, 3 * D_, t * D_, 0, 1.f);
        transpose_split_kernel<<<dim3(32, 128), 256, 0, stream>>>(
            K2 + (size_t)t * FILT_ * D_, K2Th, K2Tl, FILT_, D_, 3 * FILT_, t * FILT_, 0, 1.f);
    }
    sig_kernel<<<(L_ * D_) / 256, 256, 0, stream>>>(timesig, possig);

    embed_kernel<<<ROWS_, 256, 0, stream>>>(X, emb, state);

    dim3 gQKV(3 * D_ / 128, ROWS_ / 128);      // (24, 32)   128^2/4w, 2 blk/CU
    dim3 gWo(D_ / 64, ROWS_ / 128);            // (16, 32)   128x64/4w, 3 blk/CU
    dim3 gC1(FILT_ / 256, ROWS_ / 256);        // (16, 16)   256^2/8w, 1 blk/CU
    dim3 gC2(D_ / 256, ROWS_ / 256, 4);        // (4, 16, 4) 256^2/8w split-K=4

    for (int t = 0; t < NLAYERS_; ++t) {
        add_sig_kernel<<<NE_ / 256, 256, 0, stream>>>(state, timesig, possig, t);
        act_kernel<<<ROWS_, 256, 0, stream>>>(state, p_w, p_b, hp, rem, nup, uw);
        ln_kernel<0><<<ROWS_, 256, 0, stream>>>(state, ln1_g, ln1_b, xn1h, xn1l);

        // qkv = xn @ [0.125*Wq | Wk | Wv]  (fp32 out)
        mfma_gemm_pipe<128,128,2,2, 2, 0,0,0,0,0, 1><<<gQKV, 256, 0, stream>>>(
            xn1h, xn1l, WqkvTh, WqkvTl, qkv, nullptr, nullptr, ROWS_, 3 * D_, D_);
        vt_kernel<<<dim3(L_ / 64, H_, B_), 256, 0, stream>>>(qkv, Vth, Vtl);
        fattn_kernel<<<dim3(L_ / 128, H_, B_), 256, 0, stream>>>(qkv, Vth, Vtl, ctxh, ctxl);

        // state += ctx @ Wo
        mfma_gemm_pipe<128,64,2,2, 3, 0,0,1,0,0, 1><<<gWo, 256, 0, stream>>>(
            ctxh, ctxl, WoTh, WoTl, state, nullptr, nullptr, ROWS_, D_, D_);

        // re-zero conv halos (h region aliases qkv/Vt — now dead)
        zero_halo_kernel<<<81920 / 256, 256, 0, stream>>>(xn2ph, xn2pl, hbh, hbl);

        ln_kernel<1><<<ROWS_, 256, 0, stream>>>(state, ln2_g, ln2_b, xn2ph, xn2pl);

        // h = relu(conv1(xn2) + c1_b)  -> padded split bf16 (256^2, 8 waves)
        mfma_gemm_pipe<256,256,2,4, 2, 1,10,3,1,1, 1><<<gC1, 512, 0, stream>>>(
            xn2ph, xn2pl, K1Th, K1Tl, hbh, hbl, c1_b, ROWS_, FILT_, 3 * D_);
        // conv2 partials (256^2, 8 waves, split-K=4), then fused reduce:
        // state += sum + c2_b, prev = state*uw + prev*(1-uw)
        mfma_gemm_pipe<256,256,2,4, 2, 1,12,0,0,0, 4><<<gC2, 512, 0, stream>>>(
            hbh, hbl, K2Th, K2Tl, part, nullptr, nullptr, ROWS_, D_, 3 * FILT_);
        reduce_k_kernel<<<(int)(NE_ / 4 / 256), 256, 0, stream>>>(part, c2_b, state, prev, uw);
    }

    mean_kernel<<<(B_ * D_) / 256, 256, 0, stream>>>(prev, meanbuf);
    final_kernel<<<1, 256, 0, stream>>>(meanbuf, W_out, b_out, rem, nup, (float*)d_out);
}